// Round 15
// baseline (224.665 us; speedup 1.0000x reference)
//
#include <hip/hip_runtime.h>
#include <math.h>

#define B_   4
#define N_   512
#define T_   128
#define F_   64
#define QB   128       // q rows per block
#define NSTR (T_*F_)   // 8192 floats between consecutive n in x
#define TILE 8192      // bytes per K tile (64n x 64f bf16, blocked layout)
// blocked K-tile layout: byte(n,f) = (f>>4)*2048 + (n>>2)*128 + (n&3)*32 + (f&15)*2
#define FTILE 8192     // fallback kernel K tile

typedef __attribute__((ext_vector_type(8))) short  s8v;
typedef __attribute__((ext_vector_type(4))) float  f4v;

union F8 { s8v v; unsigned u[4]; uint2 u2[2]; };

__device__ __forceinline__ unsigned cvt_pk(float lo, float hi) {
    unsigned r;
    asm("v_cvt_pk_bf16_f32 %0, %1, %2" : "=v"(r) : "v"(lo), "v"(hi));
    return r;
}

template<int OFF>
__device__ __forceinline__ uint2 tr16(unsigned a) {
    uint2 d;
    asm volatile("ds_read_b64_tr_b16 %0, %1 offset:%2" : "=v"(d) : "v"(a), "i"(OFF));
    return d;
}

__device__ __forceinline__ void gload16(const void* g, void* l) {
    __builtin_amdgcn_global_load_lds(
        (const __attribute__((address_space(1))) void*)g,
        (__attribute__((address_space(3))) void*)l, 16, 0, 0);
}

#define EXPK 0.18033688f   // 0.125 * log2(e)

// ---- P1: x[b][n][t][f] (f32) -> xt[b][t][n][f] (bf16)  (validated R8) ----
__global__ __launch_bounds__(256)
void xpose_kernel(const float* __restrict__ x, unsigned short* __restrict__ xt)
{
    __shared__ char lds[32*1024];

    const int tid = threadIdx.x;
    const int lane = tid & 63;
    const int w    = tid >> 6;
    const int n0 = blockIdx.x * 8;
    const int t0 = blockIdx.y * 32;
    const int b  = blockIdx.z;

    const int tA = tid >> 3;
    const int f0 = (tid & 7) * 8;

    #pragma unroll
    for (int np = 0; np < 8; ++np) {
        const float* gp = x + ((size_t)(b*N_ + n0 + np)*T_ + t0 + tA)*F_ + f0;
        float4 a = *(const float4*)gp;
        float4 c = *(const float4*)(gp + 4);
        uint4 u;
        u.x = cvt_pk(a.x, a.y); u.y = cvt_pk(a.z, a.w);
        u.z = cvt_pk(c.x, c.y); u.w = cvt_pk(c.z, c.w);
        *(uint4*)(lds + tA*1024 + np*128 + ((f0*2) ^ ((tA & 7) << 4))) = u;
    }
    __syncthreads();

    #pragma unroll
    for (int p = 0; p < 8; ++p) {
        int t  = p*4 + w;
        int np = lane >> 3;
        int i  = lane & 7;
        uint4 u = *(const uint4*)(lds + t*1024 + np*128 + ((i*16) ^ ((t & 7) << 4)));
        *(uint4*)(xt + ((size_t)(b*T_ + t0 + t)*N_ + n0 + np)*F_ + i*8) = u;
    }
}

// ---- main: R11 structure (validated 76us), kt-loop unrolled x2 with literal p ----
__global__ __launch_bounds__(512, 4)
void sgcn_u2_kernel(const unsigned short* __restrict__ xt,
                    const float* __restrict__ adj,
                    const float* __restrict__ theta,
                    float* __restrict__ out)
{
    __shared__ char lds[65536];   // [0,32K): K tiles (2 streams x dbuf x 8K); [32K,64K): adj f32

    const int tid  = threadIdx.x;
    const int lane = tid & 63;
    const int w    = tid >> 6;     // 0..7
    const int s    = w >> 2;       // stream (group) 0/1
    const int wq   = w & 3;        // q sub-tile within block
    const int c15  = lane & 15;
    const int g4   = lane >> 4;

    const int bid = blockIdx.x;    // 0..1023
    const int qx  = bid & 3;
    const int tp  = bid >> 2;
    const int g   = 2*tp + s;      // this wave's group
    const int b   = g >> 7;
    const int t   = g & 127;
    const int qb  = qx*QB;
    const int q0  = qb + 32*wq;

    const unsigned short* xtg = xt + (size_t)g*N_*F_;
    char* Kbase = lds + s*(2*TILE);
    char* Abase = lds + 32768;

    // K gload source offsets (validated R10/R11)
    int soff[2];
    #pragma unroll
    for (int i = 0; i < 2; ++i) {
        int c  = wq*128 + i*64 + lane;
        int fh = c >> 7, r = c & 127;
        int nh = r >> 3, r2 = r & 7;
        soff[i] = (nh*4 + (r2 >> 1))*F_ + fh*16 + (r2 & 1)*8;
    }

    // adj gload source offsets, pre-swizzled (validated R11)
    int aoff[4];
    #pragma unroll
    for (int j = 0; j < 4; ++j) {
        int row = j*32 + w*4 + (lane >> 4);
        aoff[j] = (qb + row)*N_ + ((c15 ^ (row & 15)) << 2);
    }

    auto stageK = [&](int kt1, int p) {   // p literal at call sites
        const unsigned short* sb = xtg + (size_t)kt1*64*F_;
        #pragma unroll
        for (int i = 0; i < 2; ++i)
            gload16(sb + soff[i], Kbase + p*TILE + (wq*128 + i*64)*16);
    };
    auto stageA = [&](int kt1) {
        #pragma unroll
        for (int j = 0; j < 4; ++j)
            gload16(adj + aoff[j] + kt1*64, Abase + j*8192 + w*1024);
    };

    // QK A-frag byte addr: afoff + mt*512 + kk*4096 -> m = 16mt+c15, f = 32kk+8g4+j
    const int afoff = (g4>>1)*2048 + (c15>>2)*128 + (c15&3)*32 + (g4&1)*16;

    // ---- prologue ----
    stageK(0, 0);
    stageA(0);

    // Q B-frags (swapped QK): f = 32kk + 8g4 + j
    F8 qf[2][2];
    #pragma unroll
    for (int qt = 0; qt < 2; ++qt)
      #pragma unroll
      for (int kk = 0; kk < 2; ++kk)
        qf[qt][kk].v = *(const s8v*)(xtg + (size_t)(q0 + 16*qt + c15)*F_ + 32*kk + 8*g4);

    f4v  Oacc[4][2];
    float l_acc[2] = {0.f, 0.f};
    #pragma unroll
    for (int ft = 0; ft < 4; ++ft)
      #pragma unroll
      for (int qt = 0; qt < 2; ++qt) Oacc[ft][qt] = (f4v)0.f;

    const unsigned kvab = (unsigned)(uintptr_t)Kbase + (unsigned)(lane * 8);

    auto body = [&](int kt, int p) {   // p is a literal at both call sites
        __syncthreads();   // K[kt] + adj[kt] resident; prior reads of buffer p^1 done

        const char* bufC = Kbase + p*TILE;
        if (kt < 7) stageK(kt+1, p^1);   // async, other buffer

        // ---- QK^T + softmax (adj f32 from shared LDS tile) ----
        F8 pb[2][2];   // [qt][kk]; slot j: m = 32kk + 16*(j>=4) + 4g4 + (j&3)
        #pragma unroll
        for (int mt = 0; mt < 4; ++mt) {
            F8 af0, af1;
            af0.v = *(const s8v*)(bufC + afoff + mt*512);
            af1.v = *(const s8v*)(bufC + afoff + mt*512 + 4096);

            #pragma unroll
            for (int qt = 0; qt < 2; ++qt) {
                const int r = 32*wq + 16*qt + c15;
                float4 av = *(const float4*)(Abase + r*256 + ((((mt<<2)+g4) ^ c15) << 4));
                f4v sv = (f4v)0.f;
                sv = __builtin_amdgcn_mfma_f32_16x16x32_bf16(af0.v, qf[qt][0].v, sv, 0, 0, 0);
                sv = __builtin_amdgcn_mfma_f32_16x16x32_bf16(af1.v, qf[qt][1].v, sv, 0, 0, 0);
                float e0 = __builtin_amdgcn_exp2f(sv[0] * EXPK);
                float e1 = __builtin_amdgcn_exp2f(sv[1] * EXPK);
                float e2 = __builtin_amdgcn_exp2f(sv[2] * EXPK);
                float e3 = __builtin_amdgcn_exp2f(sv[3] * EXPK);
                l_acc[qt] += (e0 + e1) + (e2 + e3);
                pb[qt][mt>>1].u[2*(mt&1)  ] = cvt_pk(e0*av.x, e1*av.y);
                pb[qt][mt>>1].u[2*(mt&1)+1] = cvt_pk(e2*av.z, e3*av.w);
            }
        }

        __syncthreads();              // all waves done reading adj[kt]
        if (kt < 7) stageA(kt+1);     // async; lands before next top barrier

        // ---- PV via hardware transpose reads (layout validated R8) ----
        const unsigned va = kvab + (unsigned)(p*TILE);
        {
            F8 vf0, vf1, vf2, vf3;
            vf0.u2[0] = tr16<   0>(va); vf0.u2[1] = tr16< 512>(va);
            vf1.u2[0] = tr16<2048>(va); vf1.u2[1] = tr16<2560>(va);
            vf2.u2[0] = tr16<4096>(va); vf2.u2[1] = tr16<4608>(va);
            vf3.u2[0] = tr16<6144>(va); vf3.u2[1] = tr16<6656>(va);
            asm volatile("s_waitcnt lgkmcnt(0)" ::: "memory");
            __builtin_amdgcn_sched_barrier(0);
            #pragma unroll
            for (int qt = 0; qt < 2; ++qt) {
                Oacc[0][qt] = __builtin_amdgcn_mfma_f32_16x16x32_bf16(vf0.v, pb[qt][0].v, Oacc[0][qt], 0, 0, 0);
                Oacc[1][qt] = __builtin_amdgcn_mfma_f32_16x16x32_bf16(vf1.v, pb[qt][0].v, Oacc[1][qt], 0, 0, 0);
                Oacc[2][qt] = __builtin_amdgcn_mfma_f32_16x16x32_bf16(vf2.v, pb[qt][0].v, Oacc[2][qt], 0, 0, 0);
                Oacc[3][qt] = __builtin_amdgcn_mfma_f32_16x16x32_bf16(vf3.v, pb[qt][0].v, Oacc[3][qt], 0, 0, 0);
            }
        }
        {
            F8 vf0, vf1, vf2, vf3;
            vf0.u2[0] = tr16<1024>(va); vf0.u2[1] = tr16<1536>(va);
            vf1.u2[0] = tr16<3072>(va); vf1.u2[1] = tr16<3584>(va);
            vf2.u2[0] = tr16<5120>(va); vf2.u2[1] = tr16<5632>(va);
            vf3.u2[0] = tr16<7168>(va); vf3.u2[1] = tr16<7680>(va);
            asm volatile("s_waitcnt lgkmcnt(0)" ::: "memory");
            __builtin_amdgcn_sched_barrier(0);
            #pragma unroll
            for (int qt = 0; qt < 2; ++qt) {
                Oacc[0][qt] = __builtin_amdgcn_mfma_f32_16x16x32_bf16(vf0.v, pb[qt][1].v, Oacc[0][qt], 0, 0, 0);
                Oacc[1][qt] = __builtin_amdgcn_mfma_f32_16x16x32_bf16(vf1.v, pb[qt][1].v, Oacc[1][qt], 0, 0, 0);
                Oacc[2][qt] = __builtin_amdgcn_mfma_f32_16x16x32_bf16(vf2.v, pb[qt][1].v, Oacc[2][qt], 0, 0, 0);
                Oacc[3][qt] = __builtin_amdgcn_mfma_f32_16x16x32_bf16(vf3.v, pb[qt][1].v, Oacc[3][qt], 0, 0, 0);
            }
        }
    };

    // kt-loop unrolled x2: all buffer selectors are compile-time literals
    for (int kt = 0; kt < 8; kt += 2) {
        body(kt,     0);
        body(kt + 1, 1);
    }

    // ---- softmax denominators ----
    float inv[2];
    #pragma unroll
    for (int qt = 0; qt < 2; ++qt) {
        float lv = l_acc[qt];
        lv += __shfl_xor(lv, 16);
        lv += __shfl_xor(lv, 32);
        inv[qt] = 0.125f / lv;
    }

    // ---- B-frags from O^T (lane-local), scaled ----
    F8 ob[2][2];
    #pragma unroll
    for (int qt = 0; qt < 2; ++qt)
      #pragma unroll
      for (int kk = 0; kk < 2; ++kk) {
        f4v o0 = Oacc[2*kk][qt], o1 = Oacc[2*kk+1][qt];
        ob[qt][kk].u[0] = cvt_pk(o0[0]*inv[qt], o0[1]*inv[qt]);
        ob[qt][kk].u[1] = cvt_pk(o0[2]*inv[qt], o0[3]*inv[qt]);
        ob[qt][kk].u[2] = cvt_pk(o1[0]*inv[qt], o1[1]*inv[qt]);
        ob[qt][kk].u[3] = cvt_pk(o1[2]*inv[qt], o1[3]*inv[qt]);
      }

    // ---- Theta A-frags ----
    F8 tf[4][2];
    #pragma unroll
    for (int ot = 0; ot < 4; ++ot)
      #pragma unroll
      for (int kk = 0; kk < 2; ++kk) {
        const float* tp2 = theta + (size_t)(16*ot + c15)*F_ + 32*kk + 4*g4;
        float4 a = *(const float4*)tp2;
        float4 c = *(const float4*)(tp2 + 16);
        tf[ot][kk].u[0] = cvt_pk(a.x, a.y);
        tf[ot][kk].u[1] = cvt_pk(a.z, a.w);
        tf[ot][kk].u[2] = cvt_pk(c.x, c.y);
        tf[ot][kk].u[3] = cvt_pk(c.z, c.w);
      }

    // ---- R^T = Theta * (O^T * inv), relu, store ----
    f4v R[4][2];
    #pragma unroll
    for (int ot = 0; ot < 4; ++ot)
      #pragma unroll
      for (int qt = 0; qt < 2; ++qt) R[ot][qt] = (f4v)0.f;

    #pragma unroll
    for (int kk = 0; kk < 2; ++kk)
      #pragma unroll
      for (int ot = 0; ot < 4; ++ot)
        #pragma unroll
        for (int qt = 0; qt < 2; ++qt)
          R[ot][qt] = __builtin_amdgcn_mfma_f32_16x16x32_bf16(tf[ot][kk].v, ob[qt][kk].v, R[ot][qt], 0, 0, 0);

    #pragma unroll
    for (int ot = 0; ot < 4; ++ot)
      #pragma unroll
      for (int qt = 0; qt < 2; ++qt) {
        float4 v;
        v.x = fmaxf(R[ot][qt][0], 0.f);
        v.y = fmaxf(R[ot][qt][1], 0.f);
        v.z = fmaxf(R[ot][qt][2], 0.f);
        v.w = fmaxf(R[ot][qt][3], 0.f);
        int q  = q0 + 16*qt + c15;
        int fo = 16*ot + 4*g4;
        *(float4*)(out + ((size_t)(b*N_ + q)*T_ + t)*F_ + fo) = v;
      }
}

// ---- fallback (R8 kernel, self-contained, validated) ----
__global__ __launch_bounds__(256, 3)
void sgcn_fb_kernel(const float* __restrict__ x,
                    const float* __restrict__ adj,
                    const float* __restrict__ theta,
                    float* __restrict__ out)
{
    __shared__ char ldsbuf[2*FTILE];

    const int tid  = threadIdx.x;
    const int lane = tid & 63;
    const int w    = tid >> 6;
    const int c15  = lane & 15;
    const int g4   = lane >> 4;

    const int g  = blockIdx.y;
    const int b  = g >> 7;
    const int t  = g & 127;
    const int q0 = blockIdx.x*QB + 32*w;

    const float* xg = x + (size_t)b*N_*NSTR + (size_t)t*F_;

    F8 qf[2][2];
    #pragma unroll
    for (int qt = 0; qt < 2; ++qt)
      #pragma unroll
      for (int kk = 0; kk < 2; ++kk) {
        const float* qp = xg + (size_t)(q0 + 16*qt + c15)*NSTR + 32*kk + 8*g4;
        float4 a = *(const float4*)qp;
        float4 c = *(const float4*)(qp + 4);
        qf[qt][kk].u[0] = cvt_pk(a.x, a.y);
        qf[qt][kk].u[1] = cvt_pk(a.z, a.w);
        qf[qt][kk].u[2] = cvt_pk(c.x, c.y);
        qf[qt][kk].u[3] = cvt_pk(c.z, c.w);
      }

    f4v  Oacc[4][2];
    float l_acc[2] = {0.f, 0.f};
    #pragma unroll
    for (int ft = 0; ft < 4; ++ft)
      #pragma unroll
      for (int qt = 0; qt < 2; ++qt) Oacc[ft][qt] = (f4v)0.f;

    const int nrow  = tid >> 4;
    const int stoff = (c15>>2)*2048 + w*128 + g4*32 + (c15&3)*8;
    const int afoff = (g4>>1)*2048 + (c15>>2)*128 + (c15&3)*32 + (g4&1)*16;

    const float* arow0 = adj + (size_t)(q0 +      c15)*N_ + 4*g4;
    const float* arow1 = adj + (size_t)(q0 + 16 + c15)*N_ + 4*g4;

    float4 xv[4];
    auto stage = [&](char* buf) {
        #pragma unroll
        for (int it = 0; it < 4; ++it) {
            unsigned p0 = cvt_pk(xv[it].x, xv[it].y);
            unsigned p1 = cvt_pk(xv[it].z, xv[it].w);
            *(uint2*)(buf + stoff + it*512) = make_uint2(p0, p1);
        }
    };
    auto loadK = [&](int k0) {
        #pragma unroll
        for (int it = 0; it < 4; ++it)
            xv[it] = *(const float4*)(xg + (size_t)(k0 + nrow + 16*it)*NSTR + 4*c15);
    };

    loadK(0);
    stage(ldsbuf);
    const unsigned xb = (unsigned)(uintptr_t)ldsbuf;

    for (int kt = 0; kt < 8; ++kt) {
        __syncthreads();
        char* bufC = ldsbuf + (size_t)(kt & 1) * FTILE;
        char* bufN = ldsbuf + (size_t)((kt & 1) ^ 1) * FTILE;
        if (kt < 7) loadK((kt+1)*64);

        F8 pb[2][2];
        #pragma unroll
        for (int mt = 0; mt < 4; ++mt) {
            float4 av0 = *(const float4*)(arow0 + kt*64 + 16*mt);
            float4 av1 = *(const float4*)(arow1 + kt*64 + 16*mt);
            F8 af0, af1;
            af0.v = *(const s8v*)(bufC + afoff + mt*512);
            af1.v = *(const s8v*)(bufC + afoff + mt*512 + 4096);
            #pragma unroll
            for (int qt = 0; qt < 2; ++qt) {
                f4v sv = (f4v)0.f;
                sv = __builtin_amdgcn_mfma_f32_16x16x32_bf16(af0.v, qf[qt][0].v, sv, 0, 0, 0);
                sv = __builtin_amdgcn_mfma_f32_16x16x32_bf16(af1.v, qf[qt][1].v, sv, 0, 0, 0);
                float e0 = __builtin_amdgcn_exp2f(sv[0] * EXPK);
                float e1 = __builtin_amdgcn_exp2f(sv[1] * EXPK);
                float e2 = __builtin_amdgcn_exp2f(sv[2] * EXPK);
                float e3 = __builtin_amdgcn_exp2f(sv[3] * EXPK);
                l_acc[qt] += (e0 + e1) + (e2 + e3);
                float4 av = qt ? av1 : av0;
                pb[qt][mt>>1].u[2*(mt&1)  ] = cvt_pk(e0*av.x, e1*av.y);
                pb[qt][mt>>1].u[2*(mt&1)+1] = cvt_pk(e2*av.z, e3*av.w);
            }
        }

        const unsigned va = xb + (unsigned)((kt & 1) * FTILE) + (unsigned)(lane * 8);
        {
            F8 vf0, vf1, vf2, vf3;
            vf0.u2[0] = tr16<   0>(va); vf0.u2[1] = tr16< 512>(va);
            vf1.u2[0] = tr16<2048>(va); vf1.u2[1] = tr16<2560>(va);
            vf2.u2[0] = tr16<4096>(va); vf2.u2[1] = tr16<4608>(va);
            vf3.u2[0] = tr16<6144>(va); vf3.u2[1] = tr16<6656>(va);
            asm volatile("s_waitcnt lgkmcnt(0)" ::: "memory");
            __builtin_amdgcn_sched_barrier(0);
            #pragma unroll
            for (int qt = 0; qt < 2; ++qt) {
                Oacc[0][qt] = __builtin_amdgcn_mfma_f32_16x16x32_bf16(vf0.v, pb[qt][0].v, Oacc[0][qt], 0, 0, 0);
                Oacc[1][qt] = __builtin_amdgcn_mfma_f32_16x16x32_bf16(vf1.v, pb[qt][0].v, Oacc[1][qt], 0, 0, 0);
                Oacc[2][qt] = __builtin_amdgcn_mfma_f32_16x16x32_bf16(vf2.v, pb[qt][0].v, Oacc[2][qt], 0, 0, 0);
                Oacc[3][qt] = __builtin_amdgcn_mfma_f32_16x16x32_bf16(vf3.v, pb[qt][0].v, Oacc[3][qt], 0, 0, 0);
            }
        }
        {
            F8 vf0, vf1, vf2, vf3;
            vf0.u2[0] = tr16<1024>(va); vf0.u2[1] = tr16<1536>(va);
            vf1.u2[0] = tr16<3072>(va); vf1.u2[1] = tr16<3584>(va);
            vf2.u2[0] = tr16<5120>(va); vf2.u2[1] = tr16<5632>(va);
            vf3.u2[0] = tr16<7168>(va); vf3.u2[1] = tr16<7680>(va);
            asm volatile("s_waitcnt lgkmcnt(0)" ::: "memory");
            __builtin_amdgcn_sched_barrier(0);
            #pragma unroll
            for (int qt = 0; qt < 2; ++qt) {
                Oacc[0][qt] = __builtin_amdgcn_mfma_f32_16x16x32_bf16(vf0.v, pb[qt][1].v, Oacc[0][qt], 0, 0, 0);
                Oacc[1][qt] = __builtin_amdgcn_mfma_f32_16x16x32_bf16(vf1.v, pb[qt][1].v, Oacc[1][qt], 0, 0, 0);
                Oacc[2][qt] = __builtin_amdgcn_mfma_f32_16x16x32_bf16(vf2.v, pb[qt][1].v, Oacc[2][qt], 0, 0, 0);
                Oacc[3][qt] = __builtin_amdgcn_mfma_f32_16x16x32_bf16(vf3.v, pb[qt][1].v, Oacc[3][qt], 0, 0, 0);
            }
        }
        if (kt < 7) stage(bufN);
    }

    float inv[2];
    #pragma unroll
    for (int qt = 0; qt < 2; ++qt) {
        float lv = l_acc[qt];
        lv += __shfl_xor(lv, 16);
        lv += __shfl_xor(lv, 32);
        inv[qt] = 0.125f / lv;
    }

    F8 ob[2][2];
    #pragma unroll
    for (int qt = 0; qt < 2; ++qt)
      #pragma unroll
      for (int kk = 0; kk < 2; ++kk) {
        f4v o0 = Oacc[2*kk][qt], o1 = Oacc[2*kk+1][qt];
        ob[qt][kk].u[0] = cvt_pk(o0[0]*inv[qt], o0[1]*inv[qt]);
        ob[qt][kk].u[1] = cvt_pk(o0[2]*inv[qt], o0[3]*inv[qt]);
        ob[qt][kk].u[2] = cvt_pk(o1[0]*inv[qt], o1[1]*inv[qt]);
        ob[qt][kk].u[3] = cvt_pk(o1[2]*inv[qt], o1[3]*inv[qt]);
      }

    F8 tf[4][2];
    #pragma unroll
    for (int ot = 0; ot < 4; ++ot)
      #pragma unroll
      for (int kk = 0; kk < 2; ++kk) {
        const float* tp2 = theta + (size_t)(16*ot + c15)*F_ + 32*kk + 4*g4;
        float4 a = *(const float4*)tp2;
        float4 c = *(const float4*)(tp2 + 16);
        tf[ot][kk].u[0] = cvt_pk(a.x, a.y);
        tf[ot][kk].u[1] = cvt_pk(a.z, a.w);
        tf[ot][kk].u[2] = cvt_pk(c.x, c.y);
        tf[ot][kk].u[3] = cvt_pk(c.z, c.w);
      }

    f4v R[4][2];
    #pragma unroll
    for (int ot = 0; ot < 4; ++ot)
      #pragma unroll
      for (int qt = 0; qt < 2; ++qt) R[ot][qt] = (f4v)0.f;

    #pragma unroll
    for (int kk = 0; kk < 2; ++kk)
      #pragma unroll
      for (int ot = 0; ot < 4; ++ot)
        #pragma unroll
        for (int qt = 0; qt < 2; ++qt)
          R[ot][qt] = __builtin_amdgcn_mfma_f32_16x16x32_bf16(tf[ot][kk].v, ob[qt][kk].v, R[ot][qt], 0, 0, 0);

    #pragma unroll
    for (int ot = 0; ot < 4; ++ot)
      #pragma unroll
      for (int qt = 0; qt < 2; ++qt) {
        float4 v;
        v.x = fmaxf(R[ot][qt][0], 0.f);
        v.y = fmaxf(R[ot][qt][1], 0.f);
        v.z = fmaxf(R[ot][qt][2], 0.f);
        v.w = fmaxf(R[ot][qt][3], 0.f);
        int q  = q0 + 16*qt + c15;
        int fo = 16*ot + 4*g4;
        *(float4*)(out + ((size_t)(b*N_ + q)*T_ + t)*F_ + fo) = v;
      }
}

extern "C" void kernel_launch(void* const* d_in, const int* in_sizes, int n_in,
                              void* d_out, int out_size, void* d_ws, size_t ws_size,
                              hipStream_t stream) {
    const float* x     = (const float*)d_in[0];
    const float* adj   = (const float*)d_in[1];
    const float* theta = (const float*)d_in[2];
    float* out = (float*)d_out;

    const size_t need = (size_t)B_*T_*N_*F_*2;   // 33.5 MB bf16 xt
    if (ws_size >= need) {
        unsigned short* xt = (unsigned short*)d_ws;
        xpose_kernel<<<dim3(N_/8, T_/32, B_), 256, 0, stream>>>(x, xt);
        sgcn_u2_kernel<<<1024, 512, 0, stream>>>(xt, adj, theta, out);
    } else {
        dim3 grid(N_ / QB, B_ * T_);
        sgcn_fb_kernel<<<grid, 256, 0, stream>>>(x, adj, theta, out);
    }
}

// Round 16
// 182.443 us; speedup vs baseline: 1.2314x; 1.2314x over previous
//
#include <hip/hip_runtime.h>
#include <math.h>

#define B_   4
#define N_   512
#define T_   128
#define F_   64
#define QB   128       // q rows per block
#define NSTR (T_*F_)   // 8192 floats between consecutive n in x
#define TILE 8192      // bytes per K tile (64n x 64f bf16, blocked layout)
// blocked K-tile layout: byte(n,f) = (f>>4)*2048 + (n>>2)*128 + (n&3)*32 + (f&15)*2
#define FTILE 8192     // fallback kernel K tile

typedef __attribute__((ext_vector_type(8))) short  s8v;
typedef __attribute__((ext_vector_type(4))) float  f4v;

union F8 { s8v v; unsigned u[4]; uint2 u2[2]; };

__device__ __forceinline__ unsigned cvt_pk(float lo, float hi) {
    unsigned r;
    asm("v_cvt_pk_bf16_f32 %0, %1, %2" : "=v"(r) : "v"(lo), "v"(hi));
    return r;
}

template<int OFF>
__device__ __forceinline__ uint2 tr16(unsigned a) {
    uint2 d;
    asm volatile("ds_read_b64_tr_b16 %0, %1 offset:%2" : "=v"(d) : "v"(a), "i"(OFF));
    return d;
}

__device__ __forceinline__ void gload16(const void* g, void* l) {
    __builtin_amdgcn_global_load_lds(
        (const __attribute__((address_space(1))) void*)g,
        (__attribute__((address_space(3))) void*)l, 16, 0, 0);
}

#define EXPK 0.18033688f   // 0.125 * log2(e)

// ---- P1: x[b][n][t][f] (f32) -> xt[b][t][n][f] (bf16)  (validated R8) ----
__global__ __launch_bounds__(256)
void xpose_kernel(const float* __restrict__ x, unsigned short* __restrict__ xt)
{
    __shared__ char lds[32*1024];

    const int tid = threadIdx.x;
    const int lane = tid & 63;
    const int w    = tid >> 6;
    const int n0 = blockIdx.x * 8;
    const int t0 = blockIdx.y * 32;
    const int b  = blockIdx.z;

    const int tA = tid >> 3;
    const int f0 = (tid & 7) * 8;

    #pragma unroll
    for (int np = 0; np < 8; ++np) {
        const float* gp = x + ((size_t)(b*N_ + n0 + np)*T_ + t0 + tA)*F_ + f0;
        float4 a = *(const float4*)gp;
        float4 c = *(const float4*)(gp + 4);
        uint4 u;
        u.x = cvt_pk(a.x, a.y); u.y = cvt_pk(a.z, a.w);
        u.z = cvt_pk(c.x, c.y); u.w = cvt_pk(c.z, c.w);
        *(uint4*)(lds + tA*1024 + np*128 + ((f0*2) ^ ((tA & 7) << 4))) = u;
    }
    __syncthreads();

    #pragma unroll
    for (int p = 0; p < 8; ++p) {
        int t  = p*4 + w;
        int np = lane >> 3;
        int i  = lane & 7;
        uint4 u = *(const uint4*)(lds + t*1024 + np*128 + ((i*16) ^ ((t & 7) << 4)));
        *(uint4*)(xt + ((size_t)(b*T_ + t0 + t)*N_ + n0 + np)*F_ + i*8) = u;
    }
}

// ---- main: R11 structure verbatim (validated 76us) + #pragma unroll 2 on kt ----
__global__ __launch_bounds__(512, 4)
void sgcn_r16_kernel(const unsigned short* __restrict__ xt,
                     const float* __restrict__ adj,
                     const float* __restrict__ theta,
                     float* __restrict__ out)
{
    __shared__ char lds[65536];   // [0,32K): K tiles (2 streams x dbuf x 8K); [32K,64K): adj f32

    const int tid  = threadIdx.x;
    const int lane = tid & 63;
    const int w    = tid >> 6;     // 0..7
    const int s    = w >> 2;       // stream (group) 0/1
    const int wq   = w & 3;        // q sub-tile within block
    const int c15  = lane & 15;
    const int g4   = lane >> 4;

    const int bid = blockIdx.x;    // 0..1023
    const int qx  = bid & 3;
    const int tp  = bid >> 2;
    const int g   = 2*tp + s;      // this wave's group
    const int b   = g >> 7;
    const int t   = g & 127;
    const int qb  = qx*QB;
    const int q0  = qb + 32*wq;

    const unsigned short* xtg = xt + (size_t)g*N_*F_;
    char* Kbase = lds + s*(2*TILE);
    char* Abase = lds + 32768;

    // ---- Q B-frags (swapped QK): f = 32kk + 8g4 + j ----
    F8 qf[2][2];
    #pragma unroll
    for (int qt = 0; qt < 2; ++qt)
      #pragma unroll
      for (int kk = 0; kk < 2; ++kk)
        qf[qt][kk].v = *(const s8v*)(xtg + (size_t)(q0 + 16*qt + c15)*F_ + 32*kk + 8*g4);

    f4v  Oacc[4][2];
    float l_acc[2] = {0.f, 0.f};
    #pragma unroll
    for (int ft = 0; ft < 4; ++ft)
      #pragma unroll
      for (int qt = 0; qt < 2; ++qt) Oacc[ft][qt] = (f4v)0.f;

    // K gload source offsets (validated R10/R11)
    int soff[2];
    #pragma unroll
    for (int i = 0; i < 2; ++i) {
        int c  = wq*128 + i*64 + lane;
        int fh = c >> 7, r = c & 127;
        int nh = r >> 3, r2 = r & 7;
        soff[i] = (nh*4 + (r2 >> 1))*F_ + fh*16 + (r2 & 1)*8;
    }

    // adj gload source offsets, pre-swizzled (validated R11)
    int aoff[4];
    #pragma unroll
    for (int j = 0; j < 4; ++j) {
        int row = j*32 + w*4 + (lane >> 4);
        aoff[j] = (qb + row)*N_ + ((c15 ^ (row & 15)) << 2);
    }

    auto stageK = [&](int kt1, int p) {
        const unsigned short* sb = xtg + (size_t)kt1*64*F_;
        #pragma unroll
        for (int i = 0; i < 2; ++i)
            gload16(sb + soff[i], Kbase + p*TILE + (wq*128 + i*64)*16);
    };
    auto stageA = [&](int kt1) {
        #pragma unroll
        for (int j = 0; j < 4; ++j)
            gload16(adj + aoff[j] + kt1*64, Abase + j*8192 + w*1024);
    };

    // QK A-frag byte addr: afoff + mt*512 + kk*4096 -> m = 16mt+c15, f = 32kk+8g4+j
    const int afoff = (g4>>1)*2048 + (c15>>2)*128 + (c15&3)*32 + (g4&1)*16;

    // ---- prologue ----
    stageK(0, 0);
    stageA(0);

    const unsigned kvab = (unsigned)(uintptr_t)Kbase + (unsigned)(lane * 8);

    #pragma unroll 2
    for (int kt = 0; kt < 8; ++kt) {
        __syncthreads();   // K[kt] + adj[kt] resident; prior reads of buffer (kt&1)^1 done

        const char* bufC = Kbase + (size_t)(kt & 1)*TILE;
        if (kt < 7) stageK(kt+1, (kt+1) & 1);   // async, other buffer

        // ---- QK^T + softmax (adj f32 from shared LDS tile) ----
        F8 pb[2][2];   // [qt][kk]; slot j: m = 32kk + 16*(j>=4) + 4g4 + (j&3)
        #pragma unroll
        for (int mt = 0; mt < 4; ++mt) {
            F8 af0, af1;
            af0.v = *(const s8v*)(bufC + afoff + mt*512);
            af1.v = *(const s8v*)(bufC + afoff + mt*512 + 4096);

            #pragma unroll
            for (int qt = 0; qt < 2; ++qt) {
                const int r = 32*wq + 16*qt + c15;
                float4 av = *(const float4*)(Abase + r*256 + ((((mt<<2)+g4) ^ c15) << 4));
                f4v sv = (f4v)0.f;
                sv = __builtin_amdgcn_mfma_f32_16x16x32_bf16(af0.v, qf[qt][0].v, sv, 0, 0, 0);
                sv = __builtin_amdgcn_mfma_f32_16x16x32_bf16(af1.v, qf[qt][1].v, sv, 0, 0, 0);
                float e0 = __builtin_amdgcn_exp2f(sv[0] * EXPK);
                float e1 = __builtin_amdgcn_exp2f(sv[1] * EXPK);
                float e2 = __builtin_amdgcn_exp2f(sv[2] * EXPK);
                float e3 = __builtin_amdgcn_exp2f(sv[3] * EXPK);
                l_acc[qt] += (e0 + e1) + (e2 + e3);
                pb[qt][mt>>1].u[2*(mt&1)  ] = cvt_pk(e0*av.x, e1*av.y);
                pb[qt][mt>>1].u[2*(mt&1)+1] = cvt_pk(e2*av.z, e3*av.w);
            }
        }

        __syncthreads();              // all waves done reading adj[kt]
        if (kt < 7) stageA(kt+1);     // async; lands before next top barrier

        // ---- PV via hardware transpose reads (layout validated R8) ----
        const unsigned va = kvab + (unsigned)((kt & 1) * TILE);
        {
            F8 vf0, vf1, vf2, vf3;
            vf0.u2[0] = tr16<   0>(va); vf0.u2[1] = tr16< 512>(va);
            vf1.u2[0] = tr16<2048>(va); vf1.u2[1] = tr16<2560>(va);
            vf2.u2[0] = tr16<4096>(va); vf2.u2[1] = tr16<4608>(va);
            vf3.u2[0] = tr16<6144>(va); vf3.u2[1] = tr16<6656>(va);
            asm volatile("s_waitcnt lgkmcnt(0)" ::: "memory");
            __builtin_amdgcn_sched_barrier(0);
            #pragma unroll
            for (int qt = 0; qt < 2; ++qt) {
                Oacc[0][qt] = __builtin_amdgcn_mfma_f32_16x16x32_bf16(vf0.v, pb[qt][0].v, Oacc[0][qt], 0, 0, 0);
                Oacc[1][qt] = __builtin_amdgcn_mfma_f32_16x16x32_bf16(vf1.v, pb[qt][0].v, Oacc[1][qt], 0, 0, 0);
                Oacc[2][qt] = __builtin_amdgcn_mfma_f32_16x16x32_bf16(vf2.v, pb[qt][0].v, Oacc[2][qt], 0, 0, 0);
                Oacc[3][qt] = __builtin_amdgcn_mfma_f32_16x16x32_bf16(vf3.v, pb[qt][0].v, Oacc[3][qt], 0, 0, 0);
            }
        }
        {
            F8 vf0, vf1, vf2, vf3;
            vf0.u2[0] = tr16<1024>(va); vf0.u2[1] = tr16<1536>(va);
            vf1.u2[0] = tr16<3072>(va); vf1.u2[1] = tr16<3584>(va);
            vf2.u2[0] = tr16<5120>(va); vf2.u2[1] = tr16<5632>(va);
            vf3.u2[0] = tr16<7168>(va); vf3.u2[1] = tr16<7680>(va);
            asm volatile("s_waitcnt lgkmcnt(0)" ::: "memory");
            __builtin_amdgcn_sched_barrier(0);
            #pragma unroll
            for (int qt = 0; qt < 2; ++qt) {
                Oacc[0][qt] = __builtin_amdgcn_mfma_f32_16x16x32_bf16(vf0.v, pb[qt][1].v, Oacc[0][qt], 0, 0, 0);
                Oacc[1][qt] = __builtin_amdgcn_mfma_f32_16x16x32_bf16(vf1.v, pb[qt][1].v, Oacc[1][qt], 0, 0, 0);
                Oacc[2][qt] = __builtin_amdgcn_mfma_f32_16x16x32_bf16(vf2.v, pb[qt][1].v, Oacc[2][qt], 0, 0, 0);
                Oacc[3][qt] = __builtin_amdgcn_mfma_f32_16x16x32_bf16(vf3.v, pb[qt][1].v, Oacc[3][qt], 0, 0, 0);
            }
        }
    }

    // ---- softmax denominators ----
    float inv[2];
    #pragma unroll
    for (int qt = 0; qt < 2; ++qt) {
        float lv = l_acc[qt];
        lv += __shfl_xor(lv, 16);
        lv += __shfl_xor(lv, 32);
        inv[qt] = 0.125f / lv;
    }

    // ---- B-frags from O^T (lane-local), scaled ----
    F8 ob[2][2];
    #pragma unroll
    for (int qt = 0; qt < 2; ++qt)
      #pragma unroll
      for (int kk = 0; kk < 2; ++kk) {
        f4v o0 = Oacc[2*kk][qt], o1 = Oacc[2*kk+1][qt];
        ob[qt][kk].u[0] = cvt_pk(o0[0]*inv[qt], o0[1]*inv[qt]);
        ob[qt][kk].u[1] = cvt_pk(o0[2]*inv[qt], o0[3]*inv[qt]);
        ob[qt][kk].u[2] = cvt_pk(o1[0]*inv[qt], o1[1]*inv[qt]);
        ob[qt][kk].u[3] = cvt_pk(o1[2]*inv[qt], o1[3]*inv[qt]);
      }

    // ---- Theta A-frags ----
    F8 tf[4][2];
    #pragma unroll
    for (int ot = 0; ot < 4; ++ot)
      #pragma unroll
      for (int kk = 0; kk < 2; ++kk) {
        const float* tp2 = theta + (size_t)(16*ot + c15)*F_ + 32*kk + 4*g4;
        float4 a = *(const float4*)tp2;
        float4 c = *(const float4*)(tp2 + 16);
        tf[ot][kk].u[0] = cvt_pk(a.x, a.y);
        tf[ot][kk].u[1] = cvt_pk(a.z, a.w);
        tf[ot][kk].u[2] = cvt_pk(c.x, c.y);
        tf[ot][kk].u[3] = cvt_pk(c.z, c.w);
      }

    // ---- R^T = Theta * (O^T * inv), relu, store ----
    f4v R[4][2];
    #pragma unroll
    for (int ot = 0; ot < 4; ++ot)
      #pragma unroll
      for (int qt = 0; qt < 2; ++qt) R[ot][qt] = (f4v)0.f;

    #pragma unroll
    for (int kk = 0; kk < 2; ++kk)
      #pragma unroll
      for (int ot = 0; ot < 4; ++ot)
        #pragma unroll
        for (int qt = 0; qt < 2; ++qt)
          R[ot][qt] = __builtin_amdgcn_mfma_f32_16x16x32_bf16(tf[ot][kk].v, ob[qt][kk].v, R[ot][qt], 0, 0, 0);

    #pragma unroll
    for (int ot = 0; ot < 4; ++ot)
      #pragma unroll
      for (int qt = 0; qt < 2; ++qt) {
        float4 v;
        v.x = fmaxf(R[ot][qt][0], 0.f);
        v.y = fmaxf(R[ot][qt][1], 0.f);
        v.z = fmaxf(R[ot][qt][2], 0.f);
        v.w = fmaxf(R[ot][qt][3], 0.f);
        int q  = q0 + 16*qt + c15;
        int fo = 16*ot + 4*g4;
        *(float4*)(out + ((size_t)(b*N_ + q)*T_ + t)*F_ + fo) = v;
      }
}

// ---- fallback (R8 kernel, self-contained, validated) ----
__global__ __launch_bounds__(256, 3)
void sgcn_fb_kernel(const float* __restrict__ x,
                    const float* __restrict__ adj,
                    const float* __restrict__ theta,
                    float* __restrict__ out)
{
    __shared__ char ldsbuf[2*FTILE];

    const int tid  = threadIdx.x;
    const int lane = tid & 63;
    const int w    = tid >> 6;
    const int c15  = lane & 15;
    const int g4   = lane >> 4;

    const int g  = blockIdx.y;
    const int b  = g >> 7;
    const int t  = g & 127;
    const int q0 = blockIdx.x*QB + 32*w;

    const float* xg = x + (size_t)b*N_*NSTR + (size_t)t*F_;

    F8 qf[2][2];
    #pragma unroll
    for (int qt = 0; qt < 2; ++qt)
      #pragma unroll
      for (int kk = 0; kk < 2; ++kk) {
        const float* qp = xg + (size_t)(q0 + 16*qt + c15)*NSTR + 32*kk + 8*g4;
        float4 a = *(const float4*)qp;
        float4 c = *(const float4*)(qp + 4);
        qf[qt][kk].u[0] = cvt_pk(a.x, a.y);
        qf[qt][kk].u[1] = cvt_pk(a.z, a.w);
        qf[qt][kk].u[2] = cvt_pk(c.x, c.y);
        qf[qt][kk].u[3] = cvt_pk(c.z, c.w);
      }

    f4v  Oacc[4][2];
    float l_acc[2] = {0.f, 0.f};
    #pragma unroll
    for (int ft = 0; ft < 4; ++ft)
      #pragma unroll
      for (int qt = 0; qt < 2; ++qt) Oacc[ft][qt] = (f4v)0.f;

    const int nrow  = tid >> 4;
    const int stoff = (c15>>2)*2048 + w*128 + g4*32 + (c15&3)*8;
    const int afoff = (g4>>1)*2048 + (c15>>2)*128 + (c15&3)*32 + (g4&1)*16;

    const float* arow0 = adj + (size_t)(q0 +      c15)*N_ + 4*g4;
    const float* arow1 = adj + (size_t)(q0 + 16 + c15)*N_ + 4*g4;

    float4 xv[4];
    auto stage = [&](char* buf) {
        #pragma unroll
        for (int it = 0; it < 4; ++it) {
            unsigned p0 = cvt_pk(xv[it].x, xv[it].y);
            unsigned p1 = cvt_pk(xv[it].z, xv[it].w);
            *(uint2*)(buf + stoff + it*512) = make_uint2(p0, p1);
        }
    };
    auto loadK = [&](int k0) {
        #pragma unroll
        for (int it = 0; it < 4; ++it)
            xv[it] = *(const float4*)(xg + (size_t)(k0 + nrow + 16*it)*NSTR + 4*c15);
    };

    loadK(0);
    stage(ldsbuf);
    const unsigned xb = (unsigned)(uintptr_t)ldsbuf;

    for (int kt = 0; kt < 8; ++kt) {
        __syncthreads();
        char* bufC = ldsbuf + (size_t)(kt & 1) * FTILE;
        char* bufN = ldsbuf + (size_t)((kt & 1) ^ 1) * FTILE;
        if (kt < 7) loadK((kt+1)*64);

        F8 pb[2][2];
        #pragma unroll
        for (int mt = 0; mt < 4; ++mt) {
            float4 av0 = *(const float4*)(arow0 + kt*64 + 16*mt);
            float4 av1 = *(const float4*)(arow1 + kt*64 + 16*mt);
            F8 af0, af1;
            af0.v = *(const s8v*)(bufC + afoff + mt*512);
            af1.v = *(const s8v*)(bufC + afoff + mt*512 + 4096);
            #pragma unroll
            for (int qt = 0; qt < 2; ++qt) {
                f4v sv = (f4v)0.f;
                sv = __builtin_amdgcn_mfma_f32_16x16x32_bf16(af0.v, qf[qt][0].v, sv, 0, 0, 0);
                sv = __builtin_amdgcn_mfma_f32_16x16x32_bf16(af1.v, qf[qt][1].v, sv, 0, 0, 0);
                float e0 = __builtin_amdgcn_exp2f(sv[0] * EXPK);
                float e1 = __builtin_amdgcn_exp2f(sv[1] * EXPK);
                float e2 = __builtin_amdgcn_exp2f(sv[2] * EXPK);
                float e3 = __builtin_amdgcn_exp2f(sv[3] * EXPK);
                l_acc[qt] += (e0 + e1) + (e2 + e3);
                float4 av = qt ? av1 : av0;
                pb[qt][mt>>1].u[2*(mt&1)  ] = cvt_pk(e0*av.x, e1*av.y);
                pb[qt][mt>>1].u[2*(mt&1)+1] = cvt_pk(e2*av.z, e3*av.w);
            }
        }

        const unsigned va = xb + (unsigned)((kt & 1) * FTILE) + (unsigned)(lane * 8);
        {
            F8 vf0, vf1, vf2, vf3;
            vf0.u2[0] = tr16<   0>(va); vf0.u2[1] = tr16< 512>(va);
            vf1.u2[0] = tr16<2048>(va); vf1.u2[1] = tr16<2560>(va);
            vf2.u2[0] = tr16<4096>(va); vf2.u2[1] = tr16<4608>(va);
            vf3.u2[0] = tr16<6144>(va); vf3.u2[1] = tr16<6656>(va);
            asm volatile("s_waitcnt lgkmcnt(0)" ::: "memory");
            __builtin_amdgcn_sched_barrier(0);
            #pragma unroll
            for (int qt = 0; qt < 2; ++qt) {
                Oacc[0][qt] = __builtin_amdgcn_mfma_f32_16x16x32_bf16(vf0.v, pb[qt][0].v, Oacc[0][qt], 0, 0, 0);
                Oacc[1][qt] = __builtin_amdgcn_mfma_f32_16x16x32_bf16(vf1.v, pb[qt][0].v, Oacc[1][qt], 0, 0, 0);
                Oacc[2][qt] = __builtin_amdgcn_mfma_f32_16x16x32_bf16(vf2.v, pb[qt][0].v, Oacc[2][qt], 0, 0, 0);
                Oacc[3][qt] = __builtin_amdgcn_mfma_f32_16x16x32_bf16(vf3.v, pb[qt][0].v, Oacc[3][qt], 0, 0, 0);
            }
        }
        {
            F8 vf0, vf1, vf2, vf3;
            vf0.u2[0] = tr16<1024>(va); vf0.u2[1] = tr16<1536>(va);
            vf1.u2[0] = tr16<3072>(va); vf1.u2[1] = tr16<3584>(va);
            vf2.u2[0] = tr16<5120>(va); vf2.u2[1] = tr16<5632>(va);
            vf3.u2[0] = tr16<7168>(va); vf3.u2[1] = tr16<7680>(va);
            asm volatile("s_waitcnt lgkmcnt(0)" ::: "memory");
            __builtin_amdgcn_sched_barrier(0);
            #pragma unroll
            for (int qt = 0; qt < 2; ++qt) {
                Oacc[0][qt] = __builtin_amdgcn_mfma_f32_16x16x32_bf16(vf0.v, pb[qt][1].v, Oacc[0][qt], 0, 0, 0);
                Oacc[1][qt] = __builtin_amdgcn_mfma_f32_16x16x32_bf16(vf1.v, pb[qt][1].v, Oacc[1][qt], 0, 0, 0);
                Oacc[2][qt] = __builtin_amdgcn_mfma_f32_16x16x32_bf16(vf2.v, pb[qt][1].v, Oacc[2][qt], 0, 0, 0);
                Oacc[3][qt] = __builtin_amdgcn_mfma_f32_16x16x32_bf16(vf3.v, pb[qt][1].v, Oacc[3][qt], 0, 0, 0);
            }
        }
        if (kt < 7) stage(bufN);
    }

    float inv[2];
    #pragma unroll
    for (int qt = 0; qt < 2; ++qt) {
        float lv = l_acc[qt];
        lv += __shfl_xor(lv, 16);
        lv += __shfl_xor(lv, 32);
        inv[qt] = 0.125f / lv;
    }

    F8 ob[2][2];
    #pragma unroll
    for (int qt = 0; qt < 2; ++qt)
      #pragma unroll
      for (int kk = 0; kk < 2; ++kk) {
        f4v o0 = Oacc[2*kk][qt], o1 = Oacc[2*kk+1][qt];
        ob[qt][kk].u[0] = cvt_pk(o0[0]*inv[qt], o0[1]*inv[qt]);
        ob[qt][kk].u[1] = cvt_pk(o0[2]*inv[qt], o0[3]*inv[qt]);
        ob[qt][kk].u[2] = cvt_pk(o1[0]*inv[qt], o1[1]*inv[qt]);
        ob[qt][kk].u[3] = cvt_pk(o1[2]*inv[qt], o1[3]*inv[qt]);
      }

    F8 tf[4][2];
    #pragma unroll
    for (int ot = 0; ot < 4; ++ot)
      #pragma unroll
      for (int kk = 0; kk < 2; ++kk) {
        const float* tp2 = theta + (size_t)(16*ot + c15)*F_ + 32*kk + 4*g4;
        float4 a = *(const float4*)tp2;
        float4 c = *(const float4*)(tp2 + 16);
        tf[ot][kk].u[0] = cvt_pk(a.x, a.y);
        tf[ot][kk].u[1] = cvt_pk(a.z, a.w);
        tf[ot][kk].u[2] = cvt_pk(c.x, c.y);
        tf[ot][kk].u[3] = cvt_pk(c.z, c.w);
      }

    f4v R[4][2];
    #pragma unroll
    for (int ot = 0; ot < 4; ++ot)
      #pragma unroll
      for (int qt = 0; qt < 2; ++qt) R[ot][qt] = (f4v)0.f;

    #pragma unroll
    for (int kk = 0; kk < 2; ++kk)
      #pragma unroll
      for (int ot = 0; ot < 4; ++ot)
        #pragma unroll
        for (int qt = 0; qt < 2; ++qt)
          R[ot][qt] = __builtin_amdgcn_mfma_f32_16x16x32_bf16(tf[ot][kk].v, ob[qt][kk].v, R[ot][qt], 0, 0, 0);

    #pragma unroll
    for (int ot = 0; ot < 4; ++ot)
      #pragma unroll
      for (int qt = 0; qt < 2; ++qt) {
        float4 v;
        v.x = fmaxf(R[ot][qt][0], 0.f);
        v.y = fmaxf(R[ot][qt][1], 0.f);
        v.z = fmaxf(R[ot][qt][2], 0.f);
        v.w = fmaxf(R[ot][qt][3], 0.f);
        int q  = q0 + 16*qt + c15;
        int fo = 16*ot + 4*g4;
        *(float4*)(out + ((size_t)(b*N_ + q)*T_ + t)*F_ + fo) = v;
      }
}

extern "C" void kernel_launch(void* const* d_in, const int* in_sizes, int n_in,
                              void* d_out, int out_size, void* d_ws, size_t ws_size,
                              hipStream_t stream) {
    const float* x     = (const float*)d_in[0];
    const float* adj   = (const float*)d_in[1];
    const float* theta = (const float*)d_in[2];
    float* out = (float*)d_out;

    const size_t need = (size_t)B_*T_*N_*F_*2;   // 33.5 MB bf16 xt
    if (ws_size >= need) {
        unsigned short* xt = (unsigned short*)d_ws;
        xpose_kernel<<<dim3(N_/8, T_/32, B_), 256, 0, stream>>>(x, xt);
        sgcn_r16_kernel<<<1024, 512, 0, stream>>>(xt, adj, theta, out);
    } else {
        dim3 grid(N_ / QB, B_ * T_);
        sgcn_fb_kernel<<<grid, 256, 0, stream>>>(x, adj, theta, out);
    }
}

// Round 17
// 89.850 us; speedup vs baseline: 2.5004x; 2.0305x over previous
//
#include <hip/hip_runtime.h>
#include <math.h>

#define B_   4
#define N_   512
#define T_   128
#define F_   64
#define QB   128       // q rows per block
#define NSTR (T_*F_)   // 8192 floats between consecutive n in x
#define TILE 8192      // bytes per K tile (blocked layout)
// blocked K-tile layout: byte(n,f) = (f>>4)*2048 + (n>>2)*128 + (n&3)*32 + (f&15)*2

typedef __attribute__((ext_vector_type(8))) short  s8v;
typedef __attribute__((ext_vector_type(4))) float  f4v;

union F8 { s8v v; unsigned u[4]; uint2 u2[2]; };

__device__ __forceinline__ unsigned cvt_pk(float lo, float hi) {
    unsigned r;
    asm("v_cvt_pk_bf16_f32 %0, %1, %2" : "=v"(r) : "v"(lo), "v"(hi));
    return r;
}

template<int OFF>
__device__ __forceinline__ uint2 tr16(unsigned a) {
    uint2 d;
    asm volatile("ds_read_b64_tr_b16 %0, %1 offset:%2" : "=v"(d) : "v"(a), "i"(OFF));
    return d;
}

__device__ __forceinline__ void gload16(const void* g, void* l) {
    __builtin_amdgcn_global_load_lds(
        (const __attribute__((address_space(1))) void*)g,
        (__attribute__((address_space(3))) void*)l, 16, 0, 0);
}

#define EXPK 0.18033688f   // 0.125 * log2(e)

// ---- P1: x[b][n][t][f] (f32) -> xt[b][t][n][f] (bf16)  (validated R8) ----
__global__ __launch_bounds__(256)
void xpose_kernel(const float* __restrict__ x, unsigned short* __restrict__ xt)
{
    __shared__ char lds[32*1024];

    const int tid = threadIdx.x;
    const int lane = tid & 63;
    const int w    = tid >> 6;
    const int n0 = blockIdx.x * 8;
    const int t0 = blockIdx.y * 32;
    const int b  = blockIdx.z;

    const int tA = tid >> 3;
    const int f0 = (tid & 7) * 8;

    #pragma unroll
    for (int np = 0; np < 8; ++np) {
        const float* gp = x + ((size_t)(b*N_ + n0 + np)*T_ + t0 + tA)*F_ + f0;
        float4 a = *(const float4*)gp;
        float4 c = *(const float4*)(gp + 4);
        uint4 u;
        u.x = cvt_pk(a.x, a.y); u.y = cvt_pk(a.z, a.w);
        u.z = cvt_pk(c.x, c.y); u.w = cvt_pk(c.z, c.w);
        *(uint4*)(lds + tA*1024 + np*128 + ((f0*2) ^ ((tA & 7) << 4))) = u;
    }
    __syncthreads();

    #pragma unroll
    for (int p = 0; p < 8; ++p) {
        int t  = p*4 + w;
        int np = lane >> 3;
        int i  = lane & 7;
        uint4 u = *(const uint4*)(lds + t*1024 + np*128 + ((i*16) ^ ((t & 7) << 4)));
        *(uint4*)(xt + ((size_t)(b*T_ + t0 + t)*N_ + n0 + np)*F_ + i*8) = u;
    }
}

// ---- main: R11 kernel restored verbatim (validated: main 76.3us, total 89.1us) ----
__global__ __launch_bounds__(512, 4)
void sgcn_shadj2_kernel(const unsigned short* __restrict__ xt,
                        const float* __restrict__ adj,
                        const float* __restrict__ theta,
                        float* __restrict__ out)
{
    __shared__ char lds[65536];   // [0,32K): K tiles (2 streams x dbuf x 8K); [32K,64K): adj tile (f32)

    const int tid  = threadIdx.x;
    const int lane = tid & 63;
    const int w    = tid >> 6;     // 0..7
    const int s    = w >> 2;       // stream (group) 0/1
    const int wq   = w & 3;        // q sub-tile within block
    const int c15  = lane & 15;
    const int g4   = lane >> 4;

    const int bid = blockIdx.x;    // 0..1023
    const int qx  = bid & 3;
    const int tp  = bid >> 2;
    const int g   = 2*tp + s;      // this wave's group
    const int b   = g >> 7;
    const int t   = g & 127;
    const int qb  = qx*QB;
    const int q0  = qb + 32*wq;

    const unsigned short* xtg = xt + (size_t)g*N_*F_;
    char* Kbase = lds + s*(2*TILE);
    char* Abase = lds + 32768;

    // ---- Q B-frags (swapped QK): f = 32kk + 8g4 + j ----
    F8 qf[2][2];
    #pragma unroll
    for (int qt = 0; qt < 2; ++qt)
      #pragma unroll
      for (int kk = 0; kk < 2; ++kk)
        qf[qt][kk].v = *(const s8v*)(xtg + (size_t)(q0 + 16*qt + c15)*F_ + 32*kk + 8*g4);

    f4v  Oacc[4][2];
    float l_acc[2] = {0.f, 0.f};
    #pragma unroll
    for (int ft = 0; ft < 4; ++ft)
      #pragma unroll
      for (int qt = 0; qt < 2; ++qt) Oacc[ft][qt] = (f4v)0.f;

    // K gload source offsets (chunk -> (n,f0) of blocked layout; validated R10)
    int soff[2];
    #pragma unroll
    for (int i = 0; i < 2; ++i) {
        int c  = wq*128 + i*64 + lane;
        int fh = c >> 7, r = c & 127;
        int nh = r >> 3, r2 = r & 7;
        soff[i] = (nh*4 + (r2 >> 1))*F_ + fh*16 + (r2 & 1)*8;
    }

    // adj gload source offsets, pre-swizzled (m173): LDS slot (row, c16slot=lane&15)
    // holds source col16 = c16slot ^ (row&15);  layout byte(r,c16)=r*256+((c16^(r&15))<<4)
    int aoff[4];
    #pragma unroll
    for (int j = 0; j < 4; ++j) {
        int row = j*32 + w*4 + (lane >> 4);
        aoff[j] = (qb + row)*N_ + ((c15 ^ (row & 15)) << 2);
    }

    auto stageK = [&](int kt1, int p) {
        const unsigned short* sb = xtg + (size_t)kt1*64*F_;
        #pragma unroll
        for (int i = 0; i < 2; ++i)
            gload16(sb + soff[i], Kbase + p*TILE + (wq*128 + i*64)*16);
    };
    auto stageA = [&](int kt1) {
        #pragma unroll
        for (int j = 0; j < 4; ++j)
            gload16(adj + aoff[j] + kt1*64, Abase + j*8192 + w*1024);
    };

    // QK A-frag byte addr: afoff + mt*512 + kk*4096 -> m = 16mt+c15, f = 32kk+8g4+j
    const int afoff = (g4>>1)*2048 + (c15>>2)*128 + (c15&3)*32 + (g4&1)*16;

    // ---- prologue ----
    stageK(0, 0);
    stageA(0);

    for (int kt = 0; kt < 8; ++kt) {
        __syncthreads();   // vmcnt drained by compiler: K[kt] + adj[kt] resident

        const char* bufC = Kbase + (size_t)(kt & 1)*TILE;
        if (kt < 7) stageK(kt+1, (kt+1) & 1);   // async, other buffer

        // ---- QK^T + softmax (adj f32 from shared LDS tile) ----
        F8 pb[2][2];   // slot j: m = 32kk + 16*(j>=4) + 4g4 + (j&3)
        #pragma unroll
        for (int mt = 0; mt < 4; ++mt) {
            F8 af0, af1;
            af0.v = *(const s8v*)(bufC + afoff + mt*512);
            af1.v = *(const s8v*)(bufC + afoff + mt*512 + 4096);

            #pragma unroll
            for (int qt = 0; qt < 2; ++qt) {
                const int r = 32*wq + 16*qt + c15;
                float4 av = *(const float4*)(Abase + r*256 + ((((mt<<2)+g4) ^ c15) << 4));
                f4v sv = (f4v)0.f;
                sv = __builtin_amdgcn_mfma_f32_16x16x32_bf16(af0.v, qf[qt][0].v, sv, 0, 0, 0);
                sv = __builtin_amdgcn_mfma_f32_16x16x32_bf16(af1.v, qf[qt][1].v, sv, 0, 0, 0);
                float e0 = __builtin_amdgcn_exp2f(sv[0] * EXPK);
                float e1 = __builtin_amdgcn_exp2f(sv[1] * EXPK);
                float e2 = __builtin_amdgcn_exp2f(sv[2] * EXPK);
                float e3 = __builtin_amdgcn_exp2f(sv[3] * EXPK);
                l_acc[qt] += (e0 + e1) + (e2 + e3);
                pb[qt][mt>>1].u[2*(mt&1)  ] = cvt_pk(e0*av.x, e1*av.y);
                pb[qt][mt>>1].u[2*(mt&1)+1] = cvt_pk(e2*av.z, e3*av.w);
            }
        }

        __syncthreads();              // all waves done reading adj[kt]
        if (kt < 7) stageA(kt+1);     // async; lands before next top barrier

        // ---- PV via hardware transpose reads (layout validated R8) ----
        const unsigned va = (unsigned)(uintptr_t)bufC + (unsigned)(lane * 8);
        {
            F8 vf0, vf1, vf2, vf3;
            vf0.u2[0] = tr16<   0>(va); vf0.u2[1] = tr16< 512>(va);
            vf1.u2[0] = tr16<2048>(va); vf1.u2[1] = tr16<2560>(va);
            vf2.u2[0] = tr16<4096>(va); vf2.u2[1] = tr16<4608>(va);
            vf3.u2[0] = tr16<6144>(va); vf3.u2[1] = tr16<6656>(va);
            asm volatile("s_waitcnt lgkmcnt(0)" ::: "memory");
            __builtin_amdgcn_sched_barrier(0);
            #pragma unroll
            for (int qt = 0; qt < 2; ++qt) {
                Oacc[0][qt] = __builtin_amdgcn_mfma_f32_16x16x32_bf16(vf0.v, pb[qt][0].v, Oacc[0][qt], 0, 0, 0);
                Oacc[1][qt] = __builtin_amdgcn_mfma_f32_16x16x32_bf16(vf1.v, pb[qt][0].v, Oacc[1][qt], 0, 0, 0);
                Oacc[2][qt] = __builtin_amdgcn_mfma_f32_16x16x32_bf16(vf2.v, pb[qt][0].v, Oacc[2][qt], 0, 0, 0);
                Oacc[3][qt] = __builtin_amdgcn_mfma_f32_16x16x32_bf16(vf3.v, pb[qt][0].v, Oacc[3][qt], 0, 0, 0);
            }
        }
        {
            F8 vf0, vf1, vf2, vf3;
            vf0.u2[0] = tr16<1024>(va); vf0.u2[1] = tr16<1536>(va);
            vf1.u2[0] = tr16<3072>(va); vf1.u2[1] = tr16<3584>(va);
            vf2.u2[0] = tr16<5120>(va); vf2.u2[1] = tr16<5632>(va);
            vf3.u2[0] = tr16<7168>(va); vf3.u2[1] = tr16<7680>(va);
            asm volatile("s_waitcnt lgkmcnt(0)" ::: "memory");
            __builtin_amdgcn_sched_barrier(0);
            #pragma unroll
            for (int qt = 0; qt < 2; ++qt) {
                Oacc[0][qt] = __builtin_amdgcn_mfma_f32_16x16x32_bf16(vf0.v, pb[qt][1].v, Oacc[0][qt], 0, 0, 0);
                Oacc[1][qt] = __builtin_amdgcn_mfma_f32_16x16x32_bf16(vf1.v, pb[qt][1].v, Oacc[1][qt], 0, 0, 0);
                Oacc[2][qt] = __builtin_amdgcn_mfma_f32_16x16x32_bf16(vf2.v, pb[qt][1].v, Oacc[2][qt], 0, 0, 0);
                Oacc[3][qt] = __builtin_amdgcn_mfma_f32_16x16x32_bf16(vf3.v, pb[qt][1].v, Oacc[3][qt], 0, 0, 0);
            }
        }
    }

    // ---- softmax denominators ----
    float inv[2];
    #pragma unroll
    for (int qt = 0; qt < 2; ++qt) {
        float lv = l_acc[qt];
        lv += __shfl_xor(lv, 16);
        lv += __shfl_xor(lv, 32);
        inv[qt] = 0.125f / lv;
    }

    // ---- B-frags from O^T (lane-local), scaled ----
    F8 ob[2][2];
    #pragma unroll
    for (int qt = 0; qt < 2; ++qt)
      #pragma unroll
      for (int kk = 0; kk < 2; ++kk) {
        f4v o0 = Oacc[2*kk][qt], o1 = Oacc[2*kk+1][qt];
        ob[qt][kk].u[0] = cvt_pk(o0[0]*inv[qt], o0[1]*inv[qt]);
        ob[qt][kk].u[1] = cvt_pk(o0[2]*inv[qt], o0[3]*inv[qt]);
        ob[qt][kk].u[2] = cvt_pk(o1[0]*inv[qt], o1[1]*inv[qt]);
        ob[qt][kk].u[3] = cvt_pk(o1[2]*inv[qt], o1[3]*inv[qt]);
      }

    // ---- Theta A-frags ----
    F8 tf[4][2];
    #pragma unroll
    for (int ot = 0; ot < 4; ++ot)
      #pragma unroll
      for (int kk = 0; kk < 2; ++kk) {
        const float* tp2 = theta + (size_t)(16*ot + c15)*F_ + 32*kk + 4*g4;
        float4 a = *(const float4*)tp2;
        float4 c = *(const float4*)(tp2 + 16);
        tf[ot][kk].u[0] = cvt_pk(a.x, a.y);
        tf[ot][kk].u[1] = cvt_pk(a.z, a.w);
        tf[ot][kk].u[2] = cvt_pk(c.x, c.y);
        tf[ot][kk].u[3] = cvt_pk(c.z, c.w);
      }

    // ---- R^T = Theta * (O^T * inv), relu, store ----
    f4v R[4][2];
    #pragma unroll
    for (int ot = 0; ot < 4; ++ot)
      #pragma unroll
      for (int qt = 0; qt < 2; ++qt) R[ot][qt] = (f4v)0.f;

    #pragma unroll
    for (int kk = 0; kk < 2; ++kk)
      #pragma unroll
      for (int ot = 0; ot < 4; ++ot)
        #pragma unroll
        for (int qt = 0; qt < 2; ++qt)
          R[ot][qt] = __builtin_amdgcn_mfma_f32_16x16x32_bf16(tf[ot][kk].v, ob[qt][kk].v, R[ot][qt], 0, 0, 0);

    #pragma unroll
    for (int ot = 0; ot < 4; ++ot)
      #pragma unroll
      for (int qt = 0; qt < 2; ++qt) {
        float4 v;
        v.x = fmaxf(R[ot][qt][0], 0.f);
        v.y = fmaxf(R[ot][qt][1], 0.f);
        v.z = fmaxf(R[ot][qt][2], 0.f);
        v.w = fmaxf(R[ot][qt][3], 0.f);
        int q  = q0 + 16*qt + c15;
        int fo = 16*ot + 4*g4;
        *(float4*)(out + ((size_t)(b*N_ + q)*T_ + t)*F_ + fo) = v;
      }
}

// ---- fallback (R8 kernel, self-contained, validated) ----
__global__ __launch_bounds__(256, 3)
void sgcn_fb_kernel(const float* __restrict__ x,
                    const float* __restrict__ adj,
                    const float* __restrict__ theta,
                    float* __restrict__ out)
{
    __shared__ char ldsbuf[2*TILE];

    const int tid  = threadIdx.x;
    const int lane = tid & 63;
    const int w    = tid >> 6;
    const int c15  = lane & 15;
    const int g4   = lane >> 4;

    const int g  = blockIdx.y;
    const int b  = g >> 7;
    const int t  = g & 127;
    const int q0 = blockIdx.x*QB + 32*w;

    const float* xg = x + (size_t)b*N_*NSTR + (size_t)t*F_;

    F8 qf[2][2];
    #pragma unroll
    for (int qt = 0; qt < 2; ++qt)
      #pragma unroll
      for (int kk = 0; kk < 2; ++kk) {
        const float* qp = xg + (size_t)(q0 + 16*qt + c15)*NSTR + 32*kk + 8*g4;
        float4 a = *(const float4*)qp;
        float4 c = *(const float4*)(qp + 4);
        qf[qt][kk].u[0] = cvt_pk(a.x, a.y);
        qf[qt][kk].u[1] = cvt_pk(a.z, a.w);
        qf[qt][kk].u[2] = cvt_pk(c.x, c.y);
        qf[qt][kk].u[3] = cvt_pk(c.z, c.w);
      }

    f4v  Oacc[4][2];
    float l_acc[2] = {0.f, 0.f};
    #pragma unroll
    for (int ft = 0; ft < 4; ++ft)
      #pragma unroll
      for (int qt = 0; qt < 2; ++qt) Oacc[ft][qt] = (f4v)0.f;

    const int nrow  = tid >> 4;
    const int stoff = (c15>>2)*2048 + w*128 + g4*32 + (c15&3)*8;
    const int afoff = (g4>>1)*2048 + (c15>>2)*128 + (c15&3)*32 + (g4&1)*16;

    const float* arow0 = adj + (size_t)(q0 +      c15)*N_ + 4*g4;
    const float* arow1 = adj + (size_t)(q0 + 16 + c15)*N_ + 4*g4;

    float4 xv[4];
    auto stage = [&](char* buf) {
        #pragma unroll
        for (int it = 0; it < 4; ++it) {
            unsigned p0 = cvt_pk(xv[it].x, xv[it].y);
            unsigned p1 = cvt_pk(xv[it].z, xv[it].w);
            *(uint2*)(buf + stoff + it*512) = make_uint2(p0, p1);
        }
    };
    auto loadK = [&](int k0) {
        #pragma unroll
        for (int it = 0; it < 4; ++it)
            xv[it] = *(const float4*)(xg + (size_t)(k0 + nrow + 16*it)*NSTR + 4*c15);
    };

    loadK(0);
    stage(ldsbuf);
    const unsigned xb = (unsigned)(uintptr_t)ldsbuf;

    for (int kt = 0; kt < 8; ++kt) {
        __syncthreads();
        char* bufC = ldsbuf + (size_t)(kt & 1) * TILE;
        char* bufN = ldsbuf + (size_t)((kt & 1) ^ 1) * TILE;
        if (kt < 7) loadK((kt+1)*64);

        F8 pb[2][2];
        #pragma unroll
        for (int mt = 0; mt < 4; ++mt) {
            float4 av0 = *(const float4*)(arow0 + kt*64 + 16*mt);
            float4 av1 = *(const float4*)(arow1 + kt*64 + 16*mt);
            F8 af0, af1;
            af0.v = *(const s8v*)(bufC + afoff + mt*512);
            af1.v = *(const s8v*)(bufC + afoff + mt*512 + 4096);
            #pragma unroll
            for (int qt = 0; qt < 2; ++qt) {
                f4v sv = (f4v)0.f;
                sv = __builtin_amdgcn_mfma_f32_16x16x32_bf16(af0.v, qf[qt][0].v, sv, 0, 0, 0);
                sv = __builtin_amdgcn_mfma_f32_16x16x32_bf16(af1.v, qf[qt][1].v, sv, 0, 0, 0);
                float e0 = __builtin_amdgcn_exp2f(sv[0] * EXPK);
                float e1 = __builtin_amdgcn_exp2f(sv[1] * EXPK);
                float e2 = __builtin_amdgcn_exp2f(sv[2] * EXPK);
                float e3 = __builtin_amdgcn_exp2f(sv[3] * EXPK);
                l_acc[qt] += (e0 + e1) + (e2 + e3);
                float4 av = qt ? av1 : av0;
                pb[qt][mt>>1].u[2*(mt&1)  ] = cvt_pk(e0*av.x, e1*av.y);
                pb[qt][mt>>1].u[2*(mt&1)+1] = cvt_pk(e2*av.z, e3*av.w);
            }
        }

        const unsigned va = xb + (unsigned)((kt & 1) * TILE) + (unsigned)(lane * 8);
        {
            F8 vf0, vf1, vf2, vf3;
            vf0.u2[0] = tr16<   0>(va); vf0.u2[1] = tr16< 512>(va);
            vf1.u2[0] = tr16<2048>(va); vf1.u2[1] = tr16<2560>(va);
            vf2.u2[0] = tr16<4096>(va); vf2.u2[1] = tr16<4608>(va);
            vf3.u2[0] = tr16<6144>(va); vf3.u2[1] = tr16<6656>(va);
            asm volatile("s_waitcnt lgkmcnt(0)" ::: "memory");
            __builtin_amdgcn_sched_barrier(0);
            #pragma unroll
            for (int qt = 0; qt < 2; ++qt) {
                Oacc[0][qt] = __builtin_amdgcn_mfma_f32_16x16x32_bf16(vf0.v, pb[qt][0].v, Oacc[0][qt], 0, 0, 0);
                Oacc[1][qt] = __builtin_amdgcn_mfma_f32_16x16x32_bf16(vf1.v, pb[qt][0].v, Oacc[1][qt], 0, 0, 0);
                Oacc[2][qt] = __builtin_amdgcn_mfma_f32_16x16x32_bf16(vf2.v, pb[qt][0].v, Oacc[2][qt], 0, 0, 0);
                Oacc[3][qt] = __builtin_amdgcn_mfma_f32_16x16x32_bf16(vf3.v, pb[qt][0].v, Oacc[3][qt], 0, 0, 0);
            }
        }
        {
            F8 vf0, vf1, vf2, vf3;
            vf0.u2[0] = tr16<1024>(va); vf0.u2[1] = tr16<1536>(va);
            vf1.u2[0] = tr16<3072>(va); vf1.u2[1] = tr16<3584>(va);
            vf2.u2[0] = tr16<5120>(va); vf2.u2[1] = tr16<5632>(va);
            vf3.u2[0] = tr16<7168>(va); vf3.u2[1] = tr16<7680>(va);
            asm volatile("s_waitcnt lgkmcnt(0)" ::: "memory");
            __builtin_amdgcn_sched_barrier(0);
            #pragma unroll
            for (int qt = 0; qt < 2; ++qt) {
                Oacc[0][qt] = __builtin_amdgcn_mfma_f32_16x16x32_bf16(vf0.v, pb[qt][1].v, Oacc[0][qt], 0, 0, 0);
                Oacc[1][qt] = __builtin_amdgcn_mfma_f32_16x16x32_bf16(vf1.v, pb[qt][1].v, Oacc[1][qt], 0, 0, 0);
                Oacc[2][qt] = __builtin_amdgcn_mfma_f32_16x16x32_bf16(vf2.v, pb[qt][1].v, Oacc[2][qt], 0, 0, 0);
                Oacc[3][qt] = __builtin_amdgcn_mfma_f32_16x16x32_bf16(vf3.v, pb[qt][1].v, Oacc[3][qt], 0, 0, 0);
            }
        }
        if (kt < 7) stage(bufN);
    }

    float inv[2];
    #pragma unroll
    for (int qt = 0; qt < 2; ++qt) {
        float lv = l_acc[qt];
        lv += __shfl_xor(lv, 16);
        lv += __shfl_xor(lv, 32);
        inv[qt] = 0.125f / lv;
    }

    F8 ob[2][2];
    #pragma unroll
    for (int qt = 0; qt < 2; ++qt)
      #pragma unroll
      for (int kk = 0; kk < 2; ++kk) {
        f4v o0 = Oacc[2*kk][qt], o1 = Oacc[2*kk+1][qt];
        ob[qt][kk].u[0] = cvt_pk(o0[0]*inv[qt], o0[1]*inv[qt]);
        ob[qt][kk].u[1] = cvt_pk(o0[2]*inv[qt], o0[3]*inv[qt]);
        ob[qt][kk].u[2] = cvt_pk(o1[0]*inv[qt], o1[1]*inv[qt]);
        ob[qt][kk].u[3] = cvt_pk(o1[2]*inv[qt], o1[3]*inv[qt]);
      }

    F8 tf[4][2];
    #pragma unroll
    for (int ot = 0; ot < 4; ++ot)
      #pragma unroll
      for (int kk = 0; kk < 2; ++kk) {
        const float* tp2 = theta + (size_t)(16*ot + c15)*F_ + 32*kk + 4*g4;
        float4 a = *(const float4*)tp2;
        float4 c = *(const float4*)(tp2 + 16);
        tf[ot][kk].u[0] = cvt_pk(a.x, a.y);
        tf[ot][kk].u[1] = cvt_pk(a.z, a.w);
        tf[ot][kk].u[2] = cvt_pk(c.x, c.y);
        tf[ot][kk].u[3] = cvt_pk(c.z, c.w);
      }

    f4v R[4][2];
    #pragma unroll
    for (int ot = 0; ot < 4; ++ot)
      #pragma unroll
      for (int qt = 0; qt < 2; ++qt) R[ot][qt] = (f4v)0.f;

    #pragma unroll
    for (int kk = 0; kk < 2; ++kk)
      #pragma unroll
      for (int ot = 0; ot < 4; ++ot)
        #pragma unroll
        for (int qt = 0; qt < 2; ++qt)
          R[ot][qt] = __builtin_amdgcn_mfma_f32_16x16x32_bf16(tf[ot][kk].v, ob[qt][kk].v, R[ot][qt], 0, 0, 0);

    #pragma unroll
    for (int ot = 0; ot < 4; ++ot)
      #pragma unroll
      for (int qt = 0; qt < 2; ++qt) {
        float4 v;
        v.x = fmaxf(R[ot][qt][0], 0.f);
        v.y = fmaxf(R[ot][qt][1], 0.f);
        v.z = fmaxf(R[ot][qt][2], 0.f);
        v.w = fmaxf(R[ot][qt][3], 0.f);
        int q  = q0 + 16*qt + c15;
        int fo = 16*ot + 4*g4;
        *(float4*)(out + ((size_t)(b*N_ + q)*T_ + t)*F_ + fo) = v;
      }
}

extern "C" void kernel_launch(void* const* d_in, const int* in_sizes, int n_in,
                              void* d_out, int out_size, void* d_ws, size_t ws_size,
                              hipStream_t stream) {
    const float* x     = (const float*)d_in[0];
    const float* adj   = (const float*)d_in[1];
    const float* theta = (const float*)d_in[2];
    float* out = (float*)d_out;

    const size_t need = (size_t)B_*T_*N_*F_*2;   // 33.5 MB bf16 xt
    if (ws_size >= need) {
        unsigned short* xt = (unsigned short*)d_ws;
        xpose_kernel<<<dim3(N_/8, T_/32, B_), 256, 0, stream>>>(x, xt);
        sgcn_shadj2_kernel<<<1024, 512, 0, stream>>>(xt, adj, theta, out);
    } else {
        dim3 grid(N_ / QB, B_ * T_);
        sgcn_fb_kernel<<<grid, 256, 0, stream>>>(x, adj, theta, out);
    }
}

// Round 18
// 86.971 us; speedup vs baseline: 2.5832x; 1.0331x over previous
//
#include <hip/hip_runtime.h>
#include <math.h>

#define B_   4
#define N_   512
#define T_   128
#define F_   64
#define QB   128       // q rows per block
#define NSTR (T_*F_)   // 8192 floats between consecutive n in x
#define TILE 8192      // bytes per K tile (blocked layout)
// blocked K-tile layout: byte(n,f) = (f>>4)*2048 + (n>>2)*128 + (n&3)*32 + (f&15)*2

typedef __attribute__((ext_vector_type(8))) short  s8v;
typedef __attribute__((ext_vector_type(4))) float  f4v;

union F8 { s8v v; unsigned u[4]; uint2 u2[2]; };

__device__ __forceinline__ unsigned cvt_pk(float lo, float hi) {
    unsigned r;
    asm("v_cvt_pk_bf16_f32 %0, %1, %2" : "=v"(r) : "v"(lo), "v"(hi));
    return r;
}

template<int OFF>
__device__ __forceinline__ uint2 tr16(unsigned a) {
    uint2 d;
    asm volatile("ds_read_b64_tr_b16 %0, %1 offset:%2" : "=v"(d) : "v"(a), "i"(OFF));
    return d;
}

__device__ __forceinline__ void gload16(const void* g, void* l) {
    __builtin_amdgcn_global_load_lds(
        (const __attribute__((address_space(1))) void*)g,
        (__attribute__((address_space(3))) void*)l, 16, 0, 0);
}

#define EXPK 0.18033688f   // 0.125 * log2(e)

// ---- P1: x[b][n][t][f] (f32) -> xt[b][t][n][f] (bf16)  (validated R8) ----
__global__ __launch_bounds__(256)
void xpose_kernel(const float* __restrict__ x, unsigned short* __restrict__ xt)
{
    __shared__ char lds[32*1024];

    const int tid = threadIdx.x;
    const int lane = tid & 63;
    const int w    = tid >> 6;
    const int n0 = blockIdx.x * 8;
    const int t0 = blockIdx.y * 32;
    const int b  = blockIdx.z;

    const int tA = tid >> 3;
    const int f0 = (tid & 7) * 8;

    #pragma unroll
    for (int np = 0; np < 8; ++np) {
        const float* gp = x + ((size_t)(b*N_ + n0 + np)*T_ + t0 + tA)*F_ + f0;
        float4 a = *(const float4*)gp;
        float4 c = *(const float4*)(gp + 4);
        uint4 u;
        u.x = cvt_pk(a.x, a.y); u.y = cvt_pk(a.z, a.w);
        u.z = cvt_pk(c.x, c.y); u.w = cvt_pk(c.z, c.w);
        *(uint4*)(lds + tA*1024 + np*128 + ((f0*2) ^ ((tA & 7) << 4))) = u;
    }
    __syncthreads();

    #pragma unroll
    for (int p = 0; p < 8; ++p) {
        int t  = p*4 + w;
        int np = lane >> 3;
        int i  = lane & 7;
        uint4 u = *(const uint4*)(lds + t*1024 + np*128 + ((i*16) ^ ((t & 7) << 4)));
        *(uint4*)(xt + ((size_t)(b*T_ + t0 + t)*N_ + n0 + np)*F_ + i*8) = u;
    }
}

// ---- main: R11/R17 kernel + XCD-locality swizzle (qx siblings share an XCD) ----
__global__ __launch_bounds__(512, 4)
void sgcn_xcd_kernel(const unsigned short* __restrict__ xt,
                     const float* __restrict__ adj,
                     const float* __restrict__ theta,
                     float* __restrict__ out)
{
    __shared__ char lds[65536];   // [0,32K): K tiles (2 streams x dbuf x 8K); [32K,64K): adj tile (f32)

    const int tid  = threadIdx.x;
    const int lane = tid & 63;
    const int w    = tid >> 6;     // 0..7
    const int s    = w >> 2;       // stream (group) 0/1
    const int wq   = w & 3;        // q sub-tile within block
    const int c15  = lane & 15;
    const int g4   = lane >> 4;

    // XCD-aware bijective remap: the 4 qx-siblings of a tp differ by 8 in bid
    // -> same XCD (dispatch round-robins bid%8) -> shared K-stream is L2-local.
    const int bid = blockIdx.x;    // 0..1023
    const int xcd = bid & 7;
    const int rr  = bid >> 3;      // 0..127
    const int qx  = rr & 3;
    const int tp  = xcd*32 + (rr >> 2);   // 0..255, bijective

    const int g   = 2*tp + s;      // this wave's group
    const int b   = g >> 7;
    const int t   = g & 127;
    const int qb  = qx*QB;
    const int q0  = qb + 32*wq;

    const unsigned short* xtg = xt + (size_t)g*N_*F_;
    char* Kbase = lds + s*(2*TILE);
    char* Abase = lds + 32768;

    // ---- Q B-frags (swapped QK): f = 32kk + 8g4 + j ----
    F8 qf[2][2];
    #pragma unroll
    for (int qt = 0; qt < 2; ++qt)
      #pragma unroll
      for (int kk = 0; kk < 2; ++kk)
        qf[qt][kk].v = *(const s8v*)(xtg + (size_t)(q0 + 16*qt + c15)*F_ + 32*kk + 8*g4);

    f4v  Oacc[4][2];
    float l_acc[2] = {0.f, 0.f};
    #pragma unroll
    for (int ft = 0; ft < 4; ++ft)
      #pragma unroll
      for (int qt = 0; qt < 2; ++qt) Oacc[ft][qt] = (f4v)0.f;

    // K gload source offsets (chunk -> (n,f0) of blocked layout; validated R10)
    int soff[2];
    #pragma unroll
    for (int i = 0; i < 2; ++i) {
        int c  = wq*128 + i*64 + lane;
        int fh = c >> 7, r = c & 127;
        int nh = r >> 3, r2 = r & 7;
        soff[i] = (nh*4 + (r2 >> 1))*F_ + fh*16 + (r2 & 1)*8;
    }

    // adj gload source offsets, pre-swizzled (validated R11)
    int aoff[4];
    #pragma unroll
    for (int j = 0; j < 4; ++j) {
        int row = j*32 + w*4 + (lane >> 4);
        aoff[j] = (qb + row)*N_ + ((c15 ^ (row & 15)) << 2);
    }

    auto stageK = [&](int kt1, int p) {
        const unsigned short* sb = xtg + (size_t)kt1*64*F_;
        #pragma unroll
        for (int i = 0; i < 2; ++i)
            gload16(sb + soff[i], Kbase + p*TILE + (wq*128 + i*64)*16);
    };
    auto stageA = [&](int kt1) {
        #pragma unroll
        for (int j = 0; j < 4; ++j)
            gload16(adj + aoff[j] + kt1*64, Abase + j*8192 + w*1024);
    };

    // QK A-frag byte addr: afoff + mt*512 + kk*4096 -> m = 16mt+c15, f = 32kk+8g4+j
    const int afoff = (g4>>1)*2048 + (c15>>2)*128 + (c15&3)*32 + (g4&1)*16;

    // ---- prologue ----
    stageK(0, 0);
    stageA(0);

    for (int kt = 0; kt < 8; ++kt) {
        __syncthreads();   // vmcnt drained by compiler: K[kt] + adj[kt] resident

        const char* bufC = Kbase + (size_t)(kt & 1)*TILE;
        if (kt < 7) stageK(kt+1, (kt+1) & 1);   // async, other buffer

        // ---- QK^T + softmax (adj f32 from shared LDS tile) ----
        F8 pb[2][2];   // slot j: m = 32kk + 16*(j>=4) + 4g4 + (j&3)
        #pragma unroll
        for (int mt = 0; mt < 4; ++mt) {
            F8 af0, af1;
            af0.v = *(const s8v*)(bufC + afoff + mt*512);
            af1.v = *(const s8v*)(bufC + afoff + mt*512 + 4096);

            #pragma unroll
            for (int qt = 0; qt < 2; ++qt) {
                const int r = 32*wq + 16*qt + c15;
                float4 av = *(const float4*)(Abase + r*256 + ((((mt<<2)+g4) ^ c15) << 4));
                f4v sv = (f4v)0.f;
                sv = __builtin_amdgcn_mfma_f32_16x16x32_bf16(af0.v, qf[qt][0].v, sv, 0, 0, 0);
                sv = __builtin_amdgcn_mfma_f32_16x16x32_bf16(af1.v, qf[qt][1].v, sv, 0, 0, 0);
                float e0 = __builtin_amdgcn_exp2f(sv[0] * EXPK);
                float e1 = __builtin_amdgcn_exp2f(sv[1] * EXPK);
                float e2 = __builtin_amdgcn_exp2f(sv[2] * EXPK);
                float e3 = __builtin_amdgcn_exp2f(sv[3] * EXPK);
                l_acc[qt] += (e0 + e1) + (e2 + e3);
                pb[qt][mt>>1].u[2*(mt&1)  ] = cvt_pk(e0*av.x, e1*av.y);
                pb[qt][mt>>1].u[2*(mt&1)+1] = cvt_pk(e2*av.z, e3*av.w);
            }
        }

        __syncthreads();              // all waves done reading adj[kt]
        if (kt < 7) stageA(kt+1);     // async; lands before next top barrier

        // ---- PV via hardware transpose reads (layout validated R8) ----
        const unsigned va = (unsigned)(uintptr_t)bufC + (unsigned)(lane * 8);
        {
            F8 vf0, vf1, vf2, vf3;
            vf0.u2[0] = tr16<   0>(va); vf0.u2[1] = tr16< 512>(va);
            vf1.u2[0] = tr16<2048>(va); vf1.u2[1] = tr16<2560>(va);
            vf2.u2[0] = tr16<4096>(va); vf2.u2[1] = tr16<4608>(va);
            vf3.u2[0] = tr16<6144>(va); vf3.u2[1] = tr16<6656>(va);
            asm volatile("s_waitcnt lgkmcnt(0)" ::: "memory");
            __builtin_amdgcn_sched_barrier(0);
            #pragma unroll
            for (int qt = 0; qt < 2; ++qt) {
                Oacc[0][qt] = __builtin_amdgcn_mfma_f32_16x16x32_bf16(vf0.v, pb[qt][0].v, Oacc[0][qt], 0, 0, 0);
                Oacc[1][qt] = __builtin_amdgcn_mfma_f32_16x16x32_bf16(vf1.v, pb[qt][0].v, Oacc[1][qt], 0, 0, 0);
                Oacc[2][qt] = __builtin_amdgcn_mfma_f32_16x16x32_bf16(vf2.v, pb[qt][0].v, Oacc[2][qt], 0, 0, 0);
                Oacc[3][qt] = __builtin_amdgcn_mfma_f32_16x16x32_bf16(vf3.v, pb[qt][0].v, Oacc[3][qt], 0, 0, 0);
            }
        }
        {
            F8 vf0, vf1, vf2, vf3;
            vf0.u2[0] = tr16<1024>(va); vf0.u2[1] = tr16<1536>(va);
            vf1.u2[0] = tr16<3072>(va); vf1.u2[1] = tr16<3584>(va);
            vf2.u2[0] = tr16<5120>(va); vf2.u2[1] = tr16<5632>(va);
            vf3.u2[0] = tr16<7168>(va); vf3.u2[1] = tr16<7680>(va);
            asm volatile("s_waitcnt lgkmcnt(0)" ::: "memory");
            __builtin_amdgcn_sched_barrier(0);
            #pragma unroll
            for (int qt = 0; qt < 2; ++qt) {
                Oacc[0][qt] = __builtin_amdgcn_mfma_f32_16x16x32_bf16(vf0.v, pb[qt][1].v, Oacc[0][qt], 0, 0, 0);
                Oacc[1][qt] = __builtin_amdgcn_mfma_f32_16x16x32_bf16(vf1.v, pb[qt][1].v, Oacc[1][qt], 0, 0, 0);
                Oacc[2][qt] = __builtin_amdgcn_mfma_f32_16x16x32_bf16(vf2.v, pb[qt][1].v, Oacc[2][qt], 0, 0, 0);
                Oacc[3][qt] = __builtin_amdgcn_mfma_f32_16x16x32_bf16(vf3.v, pb[qt][1].v, Oacc[3][qt], 0, 0, 0);
            }
        }
    }

    // ---- softmax denominators ----
    float inv[2];
    #pragma unroll
    for (int qt = 0; qt < 2; ++qt) {
        float lv = l_acc[qt];
        lv += __shfl_xor(lv, 16);
        lv += __shfl_xor(lv, 32);
        inv[qt] = 0.125f / lv;
    }

    // ---- B-frags from O^T (lane-local), scaled ----
    F8 ob[2][2];
    #pragma unroll
    for (int qt = 0; qt < 2; ++qt)
      #pragma unroll
      for (int kk = 0; kk < 2; ++kk) {
        f4v o0 = Oacc[2*kk][qt], o1 = Oacc[2*kk+1][qt];
        ob[qt][kk].u[0] = cvt_pk(o0[0]*inv[qt], o0[1]*inv[qt]);
        ob[qt][kk].u[1] = cvt_pk(o0[2]*inv[qt], o0[3]*inv[qt]);
        ob[qt][kk].u[2] = cvt_pk(o1[0]*inv[qt], o1[1]*inv[qt]);
        ob[qt][kk].u[3] = cvt_pk(o1[2]*inv[qt], o1[3]*inv[qt]);
      }

    // ---- Theta A-frags ----
    F8 tf[4][2];
    #pragma unroll
    for (int ot = 0; ot < 4; ++ot)
      #pragma unroll
      for (int kk = 0; kk < 2; ++kk) {
        const float* tp2 = theta + (size_t)(16*ot + c15)*F_ + 32*kk + 4*g4;
        float4 a = *(const float4*)tp2;
        float4 c = *(const float4*)(tp2 + 16);
        tf[ot][kk].u[0] = cvt_pk(a.x, a.y);
        tf[ot][kk].u[1] = cvt_pk(a.z, a.w);
        tf[ot][kk].u[2] = cvt_pk(c.x, c.y);
        tf[ot][kk].u[3] = cvt_pk(c.z, c.w);
      }

    // ---- R^T = Theta * (O^T * inv), relu, store ----
    f4v R[4][2];
    #pragma unroll
    for (int ot = 0; ot < 4; ++ot)
      #pragma unroll
      for (int qt = 0; qt < 2; ++qt) R[ot][qt] = (f4v)0.f;

    #pragma unroll
    for (int kk = 0; kk < 2; ++kk)
      #pragma unroll
      for (int ot = 0; ot < 4; ++ot)
        #pragma unroll
        for (int qt = 0; qt < 2; ++qt)
          R[ot][qt] = __builtin_amdgcn_mfma_f32_16x16x32_bf16(tf[ot][kk].v, ob[qt][kk].v, R[ot][qt], 0, 0, 0);

    #pragma unroll
    for (int ot = 0; ot < 4; ++ot)
      #pragma unroll
      for (int qt = 0; qt < 2; ++qt) {
        float4 v;
        v.x = fmaxf(R[ot][qt][0], 0.f);
        v.y = fmaxf(R[ot][qt][1], 0.f);
        v.z = fmaxf(R[ot][qt][2], 0.f);
        v.w = fmaxf(R[ot][qt][3], 0.f);
        int q  = q0 + 16*qt + c15;
        int fo = 16*ot + 4*g4;
        *(float4*)(out + ((size_t)(b*N_ + q)*T_ + t)*F_ + fo) = v;
      }
}

// ---- fallback (R8 kernel, self-contained, validated) ----
__global__ __launch_bounds__(256, 3)
void sgcn_fb_kernel(const float* __restrict__ x,
                    const float* __restrict__ adj,
                    const float* __restrict__ theta,
                    float* __restrict__ out)
{
    __shared__ char ldsbuf[2*TILE];

    const int tid  = threadIdx.x;
    const int lane = tid & 63;
    const int w    = tid >> 6;
    const int c15  = lane & 15;
    const int g4   = lane >> 4;

    const int g  = blockIdx.y;
    const int b  = g >> 7;
    const int t  = g & 127;
    const int q0 = blockIdx.x*QB + 32*w;

    const float* xg = x + (size_t)b*N_*NSTR + (size_t)t*F_;

    F8 qf[2][2];
    #pragma unroll
    for (int qt = 0; qt < 2; ++qt)
      #pragma unroll
      for (int kk = 0; kk < 2; ++kk) {
        const float* qp = xg + (size_t)(q0 + 16*qt + c15)*NSTR + 32*kk + 8*g4;
        float4 a = *(const float4*)qp;
        float4 c = *(const float4*)(qp + 4);
        qf[qt][kk].u[0] = cvt_pk(a.x, a.y);
        qf[qt][kk].u[1] = cvt_pk(a.z, a.w);
        qf[qt][kk].u[2] = cvt_pk(c.x, c.y);
        qf[qt][kk].u[3] = cvt_pk(c.z, c.w);
      }

    f4v  Oacc[4][2];
    float l_acc[2] = {0.f, 0.f};
    #pragma unroll
    for (int ft = 0; ft < 4; ++ft)
      #pragma unroll
      for (int qt = 0; qt < 2; ++qt) Oacc[ft][qt] = (f4v)0.f;

    const int nrow  = tid >> 4;
    const int stoff = (c15>>2)*2048 + w*128 + g4*32 + (c15&3)*8;
    const int afoff = (g4>>1)*2048 + (c15>>2)*128 + (c15&3)*32 + (g4&1)*16;

    const float* arow0 = adj + (size_t)(q0 +      c15)*N_ + 4*g4;
    const float* arow1 = adj + (size_t)(q0 + 16 + c15)*N_ + 4*g4;

    float4 xv[4];
    auto stage = [&](char* buf) {
        #pragma unroll
        for (int it = 0; it < 4; ++it) {
            unsigned p0 = cvt_pk(xv[it].x, xv[it].y);
            unsigned p1 = cvt_pk(xv[it].z, xv[it].w);
            *(uint2*)(buf + stoff + it*512) = make_uint2(p0, p1);
        }
    };
    auto loadK = [&](int k0) {
        #pragma unroll
        for (int it = 0; it < 4; ++it)
            xv[it] = *(const float4*)(xg + (size_t)(k0 + nrow + 16*it)*NSTR + 4*c15);
    };

    loadK(0);
    stage(ldsbuf);
    const unsigned xb = (unsigned)(uintptr_t)ldsbuf;

    for (int kt = 0; kt < 8; ++kt) {
        __syncthreads();
        char* bufC = ldsbuf + (size_t)(kt & 1) * TILE;
        char* bufN = ldsbuf + (size_t)((kt & 1) ^ 1) * TILE;
        if (kt < 7) loadK((kt+1)*64);

        F8 pb[2][2];
        #pragma unroll
        for (int mt = 0; mt < 4; ++mt) {
            float4 av0 = *(const float4*)(arow0 + kt*64 + 16*mt);
            float4 av1 = *(const float4*)(arow1 + kt*64 + 16*mt);
            F8 af0, af1;
            af0.v = *(const s8v*)(bufC + afoff + mt*512);
            af1.v = *(const s8v*)(bufC + afoff + mt*512 + 4096);
            #pragma unroll
            for (int qt = 0; qt < 2; ++qt) {
                f4v sv = (f4v)0.f;
                sv = __builtin_amdgcn_mfma_f32_16x16x32_bf16(af0.v, qf[qt][0].v, sv, 0, 0, 0);
                sv = __builtin_amdgcn_mfma_f32_16x16x32_bf16(af1.v, qf[qt][1].v, sv, 0, 0, 0);
                float e0 = __builtin_amdgcn_exp2f(sv[0] * EXPK);
                float e1 = __builtin_amdgcn_exp2f(sv[1] * EXPK);
                float e2 = __builtin_amdgcn_exp2f(sv[2] * EXPK);
                float e3 = __builtin_amdgcn_exp2f(sv[3] * EXPK);
                l_acc[qt] += (e0 + e1) + (e2 + e3);
                float4 av = qt ? av1 : av0;
                pb[qt][mt>>1].u[2*(mt&1)  ] = cvt_pk(e0*av.x, e1*av.y);
                pb[qt][mt>>1].u[2*(mt&1)+1] = cvt_pk(e2*av.z, e3*av.w);
            }
        }

        const unsigned va = xb + (unsigned)((kt & 1) * TILE) + (unsigned)(lane * 8);
        {
            F8 vf0, vf1, vf2, vf3;
            vf0.u2[0] = tr16<   0>(va); vf0.u2[1] = tr16< 512>(va);
            vf1.u2[0] = tr16<2048>(va); vf1.u2[1] = tr16<2560>(va);
            vf2.u2[0] = tr16<4096>(va); vf2.u2[1] = tr16<4608>(va);
            vf3.u2[0] = tr16<6144>(va); vf3.u2[1] = tr16<6656>(va);
            asm volatile("s_waitcnt lgkmcnt(0)" ::: "memory");
            __builtin_amdgcn_sched_barrier(0);
            #pragma unroll
            for (int qt = 0; qt < 2; ++qt) {
                Oacc[0][qt] = __builtin_amdgcn_mfma_f32_16x16x32_bf16(vf0.v, pb[qt][0].v, Oacc[0][qt], 0, 0, 0);
                Oacc[1][qt] = __builtin_amdgcn_mfma_f32_16x16x32_bf16(vf1.v, pb[qt][0].v, Oacc[1][qt], 0, 0, 0);
                Oacc[2][qt] = __builtin_amdgcn_mfma_f32_16x16x32_bf16(vf2.v, pb[qt][0].v, Oacc[2][qt], 0, 0, 0);
                Oacc[3][qt] = __builtin_amdgcn_mfma_f32_16x16x32_bf16(vf3.v, pb[qt][0].v, Oacc[3][qt], 0, 0, 0);
            }
        }
        {
            F8 vf0, vf1, vf2, vf3;
            vf0.u2[0] = tr16<1024>(va); vf0.u2[1] = tr16<1536>(va);
            vf1.u2[0] = tr16<3072>(va); vf1.u2[1] = tr16<3584>(va);
            vf2.u2[0] = tr16<5120>(va); vf2.u2[1] = tr16<5632>(va);
            vf3.u2[0] = tr16<7168>(va); vf3.u2[1] = tr16<7680>(va);
            asm volatile("s_waitcnt lgkmcnt(0)" ::: "memory");
            __builtin_amdgcn_sched_barrier(0);
            #pragma unroll
            for (int qt = 0; qt < 2; ++qt) {
                Oacc[0][qt] = __builtin_amdgcn_mfma_f32_16x16x32_bf16(vf0.v, pb[qt][1].v, Oacc[0][qt], 0, 0, 0);
                Oacc[1][qt] = __builtin_amdgcn_mfma_f32_16x16x32_bf16(vf1.v, pb[qt][1].v, Oacc[1][qt], 0, 0, 0);
                Oacc[2][qt] = __builtin_amdgcn_mfma_f32_16x16x32_bf16(vf2.v, pb[qt][1].v, Oacc[2][qt], 0, 0, 0);
                Oacc[3][qt] = __builtin_amdgcn_mfma_f32_16x16x32_bf16(vf3.v, pb[qt][1].v, Oacc[3][qt], 0, 0, 0);
            }
        }
        if (kt < 7) stage(bufN);
    }

    float inv[2];
    #pragma unroll
    for (int qt = 0; qt < 2; ++qt) {
        float lv = l_acc[qt];
        lv += __shfl_xor(lv, 16);
        lv += __shfl_xor(lv, 32);
        inv[qt] = 0.125f / lv;
    }

    F8 ob[2][2];
    #pragma unroll
    for (int qt = 0; qt < 2; ++qt)
      #pragma unroll
      for (int kk = 0; kk < 2; ++kk) {
        f4v o0 = Oacc[2*kk][qt], o1 = Oacc[2*kk+1][qt];
        ob[qt][kk].u[0] = cvt_pk(o0[0]*inv[qt], o0[1]*inv[qt]);
        ob[qt][kk].u[1] = cvt_pk(o0[2]*inv[qt], o0[3]*inv[qt]);
        ob[qt][kk].u[2] = cvt_pk(o1[0]*inv[qt], o1[1]*inv[qt]);
        ob[qt][kk].u[3] = cvt_pk(o1[2]*inv[qt], o1[3]*inv[qt]);
      }

    F8 tf[4][2];
    #pragma unroll
    for (int ot = 0; ot < 4; ++ot)
      #pragma unroll
      for (int kk = 0; kk < 2; ++kk) {
        const float* tp2 = theta + (size_t)(16*ot + c15)*F_ + 32*kk + 4*g4;
        float4 a = *(const float4*)tp2;
        float4 c = *(const float4*)(tp2 + 16);
        tf[ot][kk].u[0] = cvt_pk(a.x, a.y);
        tf[ot][kk].u[1] = cvt_pk(a.z, a.w);
        tf[ot][kk].u[2] = cvt_pk(c.x, c.y);
        tf[ot][kk].u[3] = cvt_pk(c.z, c.w);
      }

    f4v R[4][2];
    #pragma unroll
    for (int ot = 0; ot < 4; ++ot)
      #pragma unroll
      for (int qt = 0; qt < 2; ++qt) R[ot][qt] = (f4v)0.f;

    #pragma unroll
    for (int kk = 0; kk < 2; ++kk)
      #pragma unroll
      for (int ot = 0; ot < 4; ++ot)
        #pragma unroll
        for (int qt = 0; qt < 2; ++qt)
          R[ot][qt] = __builtin_amdgcn_mfma_f32_16x16x32_bf16(tf[ot][kk].v, ob[qt][kk].v, R[ot][qt], 0, 0, 0);

    #pragma unroll
    for (int ot = 0; ot < 4; ++ot)
      #pragma unroll
      for (int qt = 0; qt < 2; ++qt) {
        float4 v;
        v.x = fmaxf(R[ot][qt][0], 0.f);
        v.y = fmaxf(R[ot][qt][1], 0.f);
        v.z = fmaxf(R[ot][qt][2], 0.f);
        v.w = fmaxf(R[ot][qt][3], 0.f);
        int q  = q0 + 16*qt + c15;
        int fo = 16*ot + 4*g4;
        *(float4*)(out + ((size_t)(b*N_ + q)*T_ + t)*F_ + fo) = v;
      }
}

extern "C" void kernel_launch(void* const* d_in, const int* in_sizes, int n_in,
                              void* d_out, int out_size, void* d_ws, size_t ws_size,
                              hipStream_t stream) {
    const float* x     = (const float*)d_in[0];
    const float* adj   = (const float*)d_in[1];
    const float* theta = (const float*)d_in[2];
    float* out = (float*)d_out;

    const size_t need = (size_t)B_*T_*N_*F_*2;   // 33.5 MB bf16 xt
    if (ws_size >= need) {
        unsigned short* xt = (unsigned short*)d_ws;
        xpose_kernel<<<dim3(N_/8, T_/32, B_), 256, 0, stream>>>(x, xt);
        sgcn_xcd_kernel<<<1024, 512, 0, stream>>>(xt, adj, theta, out);
    } else {
        dim3 grid(N_ / QB, B_ * T_);
        sgcn_fb_kernel<<<grid, 256, 0, stream>>>(x, adj, theta, out);
    }
}